// Round 1
// 1036.938 us; speedup vs baseline: 1.0383x; 1.0383x over previous
//
#include <hip/hip_runtime.h>
#include <hip/hip_bf16.h>

#define B_ 4
#define N_ 8192
#define D_ 512
#define H_ 8
#define DH_ 64
#define M_ 256
#define LCH 32
#define KER_ 33
#define NSPLIT 16
#define CS (N_/NSPLIT)   // 512 cols per split chunk

typedef __hip_bfloat16 bf16;
typedef __attribute__((ext_vector_type(8))) short short8;
typedef __attribute__((ext_vector_type(4))) float f32x4;

__device__ __forceinline__ float bf2f(bf16 h){ return __bfloat162float(h); }
__device__ __forceinline__ bf16 f2bf(float f){ return __float2bfloat16(f); }
__device__ __forceinline__ f32x4 mfma16(short8 a, short8 b, f32x4 c){
  return __builtin_amdgcn_mfma_f32_16x16x32_bf16(a, b, c, 0, 0, 0);
}

// ---------------- LayerNorm: x (b,n,512) fp32 -> xn bf16 ----------------
__global__ __launch_bounds__(256) void k_layernorm(const float* __restrict__ x,
    const float* __restrict__ gamma, const float* __restrict__ beta,
    bf16* __restrict__ xn){
  int row = blockIdx.x;
  const float* xr = x + (size_t)row * D_;
  bf16* o = xn + (size_t)row * D_;
  int t = threadIdx.x;
  float v0 = xr[t], v1 = xr[t+256];
  float s = v0+v1, ss = v0*v0 + v1*v1;
  __shared__ float sh[8];
  for (int off=32; off; off>>=1){ s += __shfl_xor(s,off); ss += __shfl_xor(ss,off); }
  int lane = t&63, wid = t>>6;
  if (lane==0){ sh[wid] = s; sh[wid+4] = ss; }
  __syncthreads();
  float S  = sh[0]+sh[1]+sh[2]+sh[3];
  float SS = sh[4]+sh[5]+sh[6]+sh[7];
  float mu = S*(1.f/D_);
  float var = SS*(1.f/D_) - mu*mu;
  float rs = rsqrtf(var + 1e-5f);
  o[t]     = f2bf((v0-mu)*rs*gamma[t]     + beta[t]);
  o[t+256] = f2bf((v1-mu)*rs*gamma[t+256] + beta[t+256]);
}

// ---------------- W transpose+convert: W (RxC fp32) -> WT (CxR bf16) ----------------
__global__ __launch_bounds__(256) void k_wt(const float* __restrict__ W, bf16* __restrict__ WT,
    int R, int C){
  int c0 = blockIdx.x*64, r0 = blockIdx.y*64;
  __shared__ float tile[64][65];
  int t = threadIdx.x;
  for (int i=t;i<4096;i+=256){ int r=i>>6, c=i&63; tile[r][c] = W[(size_t)(r0+r)*C + c0+c]; }
  __syncthreads();
  for (int i=t;i<512;i+=256){
    int c=i>>3, rg=i&7;
    short8 o;
    #pragma unroll
    for (int j=0;j<8;j++) ((bf16*)&o)[j] = f2bf(tile[rg*8+j][c]);
    *(short8*)&WT[(size_t)(c0+c)*R + r0 + rg*8] = o;
  }
}

// ---------------- QKV GEMM (MFMA, LDS-staged 128x128 tile): xn @ WT^T -> q,k,v ----------------
__global__ __launch_bounds__(256) void k_mm_qkv2(const bf16* __restrict__ A, const bf16* __restrict__ WT,
    bf16* __restrict__ qbuf, bf16* __restrict__ kbuf, bf16* __restrict__ vbuf){
  __shared__ __align__(16) bf16 As[128][72];
  __shared__ __align__(16) bf16 Bs[128][72];
  int t = threadIdx.x;
  int w = t>>6, lane = t&63, qd = lane>>4, n = lane&15;
  int wm = w>>1, wn = w&1;
  int r0 = blockIdx.x*128, c0 = blockIdx.y*128;
  f32x4 acc[4][4];
  #pragma unroll
  for (int i=0;i<4;i++)
    #pragma unroll
    for (int j=0;j<4;j++) acc[i][j] = (f32x4){0.f,0.f,0.f,0.f};
  int srow = t>>3, skc = t&7;
  for (int k0=0; k0<512; k0+=64){
    #pragma unroll
    for (int ch=0; ch<4; ch++){
      int m = ch*32 + srow;
      *(short8*)&As[m][skc*8] = *(const short8*)&A[(size_t)(r0+m)*512 + k0 + skc*8];
      *(short8*)&Bs[m][skc*8] = *(const short8*)&WT[(size_t)(c0+m)*512 + k0 + skc*8];
    }
    __syncthreads();
    #pragma unroll
    for (int ksub=0; ksub<2; ksub++){
      short8 af[4], bfr[4];
      #pragma unroll
      for (int i=0;i<4;i++) af[i]  = *(const short8*)&As[wm*64+i*16+n][ksub*32+qd*8];
      #pragma unroll
      for (int j=0;j<4;j++) bfr[j] = *(const short8*)&Bs[wn*64+j*16+n][ksub*32+qd*8];
      #pragma unroll
      for (int i=0;i<4;i++)
        #pragma unroll
        for (int j=0;j<4;j++) acc[i][j] = mfma16(af[i], bfr[j], acc[i][j]);
    }
    __syncthreads();
  }
  int part = c0 >> 9;
  bf16* dst = (part==0)? qbuf : (part==1)? kbuf : vbuf;
  float scale = (part==0)? 0.125f : 1.f;
  #pragma unroll
  for (int i=0;i<4;i++){
    #pragma unroll
    for (int j=0;j<4;j++){
      int c = c0 + wn*64 + j*16 + n;
      int cc = c & 511, h = cc>>6, dh = cc&63;
      #pragma unroll
      for (int rg=0; rg<4; rg++){
        int r = r0 + wm*64 + i*16 + qd*4 + rg;
        int b = r >> 13, nn = r & 8191;
        dst[(((size_t)(b*H_+h))*N_ + nn)*DH_ + dh] = f2bf(acc[i][j][rg]*scale);
      }
    }
  }
}

// ---------------- v -> vT tiled transpose (64x64) ----------------
__global__ __launch_bounds__(256) void k_transp_v(const bf16* __restrict__ v, bf16* __restrict__ vT){
  int bh = blockIdx.y, n0 = blockIdx.x*64;
  __shared__ bf16 tile[64][72];
  const bf16* vb = v + (size_t)bh*N_*DH_;
  int t = threadIdx.x;
  for (int i=t; i<512; i+=256){
    int r = i>>3, cg = i&7;
    *(short8*)&tile[r][cg*8] = *(const short8*)&vb[(size_t)(n0+r)*DH_ + cg*8];
  }
  __syncthreads();
  bf16* ob = vT + (size_t)bh*DH_*N_;
  for (int i=t; i<512; i+=256){
    int dh = i>>3, ng = i&7;
    short8 o;
    #pragma unroll
    for (int j=0;j<8;j++) ((bf16*)&o)[j] = tile[ng*8+j][dh];
    *(short8*)&ob[(size_t)dh*N_ + n0 + ng*8] = o;
  }
}

// ---------------- landmark means over contiguous 32-row chunks ----------------
__global__ __launch_bounds__(64) void k_landmark(const bf16* __restrict__ q, const bf16* __restrict__ k,
    bf16* __restrict__ ql, bf16* __restrict__ kl){
  int bhm = blockIdx.x;
  int bh = bhm >> 8, m = bhm & 255;
  int dh = threadIdx.x;
  const bf16* qp = q + ((size_t)bh*N_ + (size_t)m*LCH)*DH_ + dh;
  const bf16* kp = k + ((size_t)bh*N_ + (size_t)m*LCH)*DH_ + dh;
  float sq=0.f, sk=0.f;
  #pragma unroll
  for (int j=0;j<LCH;j++){ sq += bf2f(qp[(size_t)j*DH_]); sk += bf2f(kp[(size_t)j*DH_]); }
  ql[((size_t)bh*M_ + m)*DH_ + dh] = f2bf(sq*(1.f/LCH));
  kl[((size_t)bh*M_ + m)*DH_ + dh] = f2bf(sk*(1.f/LCH));
}

// ---------------- attn2 = softmax(q_l @ k_l^T) rows (fp32 out) ----------------
__global__ __launch_bounds__(256) void k_attn2(const bf16* __restrict__ ql, const bf16* __restrict__ kl,
    float* __restrict__ A2){
  int bhm = blockIdx.x;
  int bh = bhm >> 8, m = bhm & 255;
  int t = threadIdx.x;
  __shared__ float qrow[64];
  __shared__ float sh[4];
  if (t < 64) qrow[t] = bf2f(ql[((size_t)bh*M_ + m)*DH_ + t]);
  __syncthreads();
  const bf16* krow = kl + ((size_t)bh*M_ + t)*DH_;
  float s = 0.f;
  #pragma unroll
  for (int i=0;i<64;i++) s += qrow[i]*bf2f(krow[i]);
  float mx = s;
  for (int off=32; off; off>>=1) mx = fmaxf(mx, __shfl_xor(mx, off));
  if ((t&63)==0) sh[t>>6] = mx;
  __syncthreads();
  mx = fmaxf(fmaxf(sh[0],sh[1]), fmaxf(sh[2],sh[3]));
  float e = expf(s - mx);
  float sum = e;
  for (int off=32; off; off>>=1) sum += __shfl_xor(sum, off);
  __syncthreads();
  if ((t&63)==0) sh[t>>6] = sum;
  __syncthreads();
  sum = sh[0]+sh[1]+sh[2]+sh[3];
  A2[((size_t)bh*M_ + m)*M_ + t] = e/sum;
}

// ---------------- pinv init: Z = A^T / (max_rowsum * max_colsum) ----------------
__global__ __launch_bounds__(256) void k_pinv_init(const float* __restrict__ A2, float* __restrict__ Z){
  int bh = blockIdx.x;
  int t = threadIdx.x;
  const float* Ab = A2 + (size_t)bh*M_*M_;
  float* Zb = Z + (size_t)bh*M_*M_;
  float cs=0.f, rsm=0.f;
  for (int r=0;r<M_;r++) cs += fabsf(Ab[(size_t)r*M_ + t]);
  for (int c=0;c<M_;c++) rsm += fabsf(Ab[(size_t)t*M_ + c]);
  __shared__ float sh[4];
  float v = cs;
  for (int off=32; off; off>>=1) v = fmaxf(v, __shfl_xor(v, off));
  if ((t&63)==0) sh[t>>6] = v;
  __syncthreads();
  float maxc = fmaxf(fmaxf(sh[0],sh[1]), fmaxf(sh[2],sh[3]));
  __syncthreads();
  v = rsm;
  for (int off=32; off; off>>=1) v = fmaxf(v, __shfl_xor(v, off));
  if ((t&63)==0) sh[t>>6] = v;
  __syncthreads();
  float maxr = fmaxf(fmaxf(sh[0],sh[1]), fmaxf(sh[2],sh[3]));
  float inv = 1.f/(maxr*maxc);
  for (int r=0;r<M_;r++) Zb[(size_t)r*M_ + t] = Ab[(size_t)t*M_ + r]*inv;
}

// ---------------- pinv GEMM (split-precision bf16 MFMA) ----------------
__global__ __launch_bounds__(256) void k_gemm_pm(float* __restrict__ C, const float* __restrict__ A,
    const float* __restrict__ Bm, float bDiag, int bNeg, float cDiag, int cNeg, float cScale){
  int bh = blockIdx.y;
  int tm = blockIdx.x >> 2, tn = blockIdx.x & 3;
  const float* Ab = A  + (size_t)bh*65536;
  const float* Bb = Bm + (size_t)bh*65536;
  float* Cb = C + (size_t)bh*65536;
  __shared__ __align__(16) bf16 Ah[64][72];
  __shared__ __align__(16) bf16 Al[64][72];
  __shared__ __align__(16) bf16 Bh[64][72];
  __shared__ __align__(16) bf16 Bl[64][72];
  int t = threadIdx.x;
  int w = t>>6, lane = t&63, qd = lane>>4, n = lane&15;
  int wm = w>>1, wn = w&1;
  int r0 = tm*64, c0 = tn*64;
  f32x4 acc[2][2];
  #pragma unroll
  for (int i=0;i<2;i++)
    #pragma unroll
    for (int j=0;j<2;j++) acc[i][j] = (f32x4){0.f,0.f,0.f,0.f};
  int srow = t>>3, skc = t&7;
  for (int k0=0; k0<256; k0+=64){
    #pragma unroll
    for (int ch=0; ch<2; ch++){
      int m = ch*32 + srow;
      short8 vh, vl;
      const float* ap = &Ab[(size_t)(r0+m)*256 + k0 + skc*8];
      #pragma unroll
      for (int j=0;j<8;j++){
        float x = ap[j];
        bf16 h = f2bf(x);
        ((bf16*)&vh)[j] = h;
        ((bf16*)&vl)[j] = f2bf(x - bf2f(h));
      }
      *(short8*)&Ah[m][skc*8] = vh;
      *(short8*)&Al[m][skc*8] = vl;
      const float* bp = &Bb[(size_t)(k0+m)*256 + c0 + skc*8];
      int kr = k0 + m;
      #pragma unroll
      for (int j=0;j<8;j++){
        float x = bp[j];
        if (bNeg) x = (kr == (c0 + skc*8 + j) ? bDiag : 0.f) - x;
        bf16 h = f2bf(x);
        ((bf16*)&vh)[j] = h;
        ((bf16*)&vl)[j] = f2bf(x - bf2f(h));
      }
      #pragma unroll
      for (int j=0;j<8;j++){
        Bh[skc*8+j][m] = ((bf16*)&vh)[j];
        Bl[skc*8+j][m] = ((bf16*)&vl)[j];
      }
    }
    __syncthreads();
    #pragma unroll
    for (int ksub=0; ksub<2; ksub++){
      short8 afh[2], afl[2], bfh[2], bfl[2];
      #pragma unroll
      for (int i=0;i<2;i++){
        afh[i] = *(const short8*)&Ah[wm*32+i*16+n][ksub*32+qd*8];
        afl[i] = *(const short8*)&Al[wm*32+i*16+n][ksub*32+qd*8];
      }
      #pragma unroll
      for (int j=0;j<2;j++){
        bfh[j] = *(const short8*)&Bh[wn*32+j*16+n][ksub*32+qd*8];
        bfl[j] = *(const short8*)&Bl[wn*32+j*16+n][ksub*32+qd*8];
      }
      #pragma unroll
      for (int i=0;i<2;i++)
        #pragma unroll
        for (int j=0;j<2;j++){
          acc[i][j] = mfma16(afl[i], bfh[j], acc[i][j]);
          acc[i][j] = mfma16(afh[i], bfl[j], acc[i][j]);
          acc[i][j] = mfma16(afh[i], bfh[j], acc[i][j]);
        }
    }
    __syncthreads();
  }
  #pragma unroll
  for (int i=0;i<2;i++){
    #pragma unroll
    for (int j=0;j<2;j++){
      int cidx = c0 + wn*32 + j*16 + n;
      #pragma unroll
      for (int rg=0; rg<4; rg++){
        int r = r0 + wm*32 + i*16 + qd*4 + rg;
        float r_ = acc[i][j][rg];
        if (cNeg) r_ = ((r==cidx)? cDiag : 0.f) - r_;
        Cb[(size_t)r*256 + cidx] = r_*cScale;
      }
    }
  }
}

// ---------------- batched GEMM 256x64x256: z2T = (Z @ kv3)^T ----------------
__global__ __launch_bounds__(256) void k_gemm_z2(bf16* __restrict__ z2t, const float* __restrict__ A,
    const bf16* __restrict__ Bm){
  int bh = blockIdx.y;
  int tm = blockIdx.x;
  const float* Ab = A  + (size_t)bh*65536;
  const bf16* Bb = Bm + (size_t)bh*M_*DH_;
  __shared__ float As[16][68];
  __shared__ float Bs[16][64];
  int t = threadIdx.x, tx = t&15, ty = t>>4;
  int r0 = tm*64;
  float acc[4][4] = {};
  for (int k0=0;k0<256;k0+=16){
    for (int i=t;i<1024;i+=256){
      int m=i>>4, kq=i&15;
      As[kq][m] = Ab[(size_t)(r0+m)*256 + k0+kq];
      int nn=i&63, k2=i>>6;
      Bs[k2][nn] = bf2f(Bb[(size_t)(k0+k2)*64 + nn]);
    }
    __syncthreads();
    #pragma unroll
    for (int kq=0;kq<16;kq++){
      float a0[4], b0[4];
      #pragma unroll
      for (int i=0;i<4;i++) a0[i] = As[kq][ty*4+i];
      #pragma unroll
      for (int j=0;j<4;j++) b0[j] = Bs[kq][tx*4+j];
      #pragma unroll
      for (int i=0;i<4;i++)
        #pragma unroll
        for (int j=0;j<4;j++) acc[i][j] += a0[i]*b0[j];
    }
    __syncthreads();
  }
  #pragma unroll
  for (int i=0;i<4;i++){
    int r = r0+ty*4+i;
    #pragma unroll
    for (int j=0;j<4;j++)
      z2t[(size_t)bh*16384 + (size_t)(tx*4+j)*256 + r] = f2bf(acc[i][j]);
  }
}

// ---------------- attn3 flash, flash-decoding split over columns ----------------
// Grid (NSPLIT, B*H). Block: 4 waves, wave w owns rows w*64..w*64+63 (4 row-tiles of 16).
// Block scans a disjoint CS=512-col chunk -> K/VT fetched exactly once from HBM.
// 64-col tiles amortize softmax reductions; 4 row-tiles/wave give ILP to hide dep chains.
__global__ __launch_bounds__(256, 2) void k_flash_split(const bf16* __restrict__ Q,
    const bf16* __restrict__ K, const bf16* __restrict__ VT,
    float* __restrict__ OP, float* __restrict__ MP, float* __restrict__ LP){
  int bh = blockIdx.y;
  int sp = blockIdx.x;
  int t = threadIdx.x, w = t>>6, lane = t&63, qd = lane>>4, n = lane&15;
  int r0 = w*64;
  const size_t Qoff = ((size_t)bh*M_ + r0)*DH_;
  const size_t Koff = ((size_t)bh*N_ + (size_t)sp*CS)*DH_;
  const size_t Voff = (size_t)bh*DH_*N_ + (size_t)sp*CS;
  __shared__ __align__(16) bf16 pbuf[4][4][16][72];   // [wave][rowtile][row][64 cols + pad]
  short8 aq[4][2];
  #pragma unroll
  for (int rt=0; rt<4; rt++){
    aq[rt][0] = *(const short8*)&Q[Qoff + (size_t)(rt*16+n)*DH_ + qd*8];
    aq[rt][1] = *(const short8*)&Q[Qoff + (size_t)(rt*16+n)*DH_ + 32 + qd*8];
  }
  f32x4 o[4][4];          // [rowtile][dh-group]
  float mrun[4][4], lrun[4][4]; // [rowtile][rg]
  #pragma unroll
  for (int rt=0; rt<4; rt++){
    #pragma unroll
    for (int j=0;j<4;j++){ o[rt][j] = (f32x4){0.f,0.f,0.f,0.f}; mrun[rt][j] = -1e30f; lrun[rt][j] = 0.f; }
  }
  for (int tl=0; tl<CS/64; ++tl){
    const bf16* kp = K + Koff + (size_t)(tl*64)*DH_;
    short8 kb[4][2];
    #pragma unroll
    for (int cg=0; cg<4; cg++){
      kb[cg][0] = *(const short8*)&kp[(size_t)(cg*16+n)*DH_ + qd*8];
      kb[cg][1] = *(const short8*)&kp[(size_t)(cg*16+n)*DH_ + 32 + qd*8];
    }
    // phase 1: QK^T + online softmax + P->LDS + rescale accumulators
    #pragma unroll
    for (int rt=0; rt<4; rt++){
      f32x4 s[4];
      #pragma unroll
      for (int cg=0; cg<4; cg++){
        f32x4 z = (f32x4){0.f,0.f,0.f,0.f};
        z = mfma16(aq[rt][0], kb[cg][0], z);
        z = mfma16(aq[rt][1], kb[cg][1], z);
        s[cg] = z;
      }
      float alpha[4];
      #pragma unroll
      for (int rg=0; rg<4; rg++){
        float smax = fmaxf(fmaxf(s[0][rg],s[1][rg]), fmaxf(s[2][rg],s[3][rg]));
        smax = fmaxf(smax, __shfl_xor(smax, 1));
        smax = fmaxf(smax, __shfl_xor(smax, 2));
        smax = fmaxf(smax, __shfl_xor(smax, 4));
        smax = fmaxf(smax, __shfl_xor(smax, 8));
        float mn = fmaxf(mrun[rt][rg], smax);
        float p0 = __expf(s[0][rg]-mn), p1 = __expf(s[1][rg]-mn);
        float p2 = __expf(s[2][rg]-mn), p3 = __expf(s[3][rg]-mn);
        float ts = p0+p1+p2+p3;
        ts += __shfl_xor(ts,1); ts += __shfl_xor(ts,2);
        ts += __shfl_xor(ts,4); ts += __shfl_xor(ts,8);
        float al = __expf(mrun[rt][rg]-mn);
        lrun[rt][rg] = lrun[rt][rg]*al + ts;
        mrun[rt][rg] = mn;
        alpha[rg] = al;
        pbuf[w][rt][qd*4+rg][n]    = f2bf(p0);
        pbuf[w][rt][qd*4+rg][16+n] = f2bf(p1);
        pbuf[w][rt][qd*4+rg][32+n] = f2bf(p2);
        pbuf[w][rt][qd*4+rg][48+n] = f2bf(p3);
      }
      #pragma unroll
      for (int dg=0; dg<4; dg++)
        #pragma unroll
        for (int rg=0; rg<4; rg++) o[rt][dg][rg] *= alpha[rg];
    }
    // phase 2: PV
    const bf16* vp = VT + Voff + tl*64 + qd*8;
    short8 vb[4][2];
    #pragma unroll
    for (int dg=0; dg<4; dg++){
      vb[dg][0] = *(const short8*)&vp[(size_t)(dg*16+n)*N_];
      vb[dg][1] = *(const short8*)&vp[(size_t)(dg*16+n)*N_ + 32];
    }
    #pragma unroll
    for (int rt=0; rt<4; rt++){
      short8 ap0 = *(const short8*)&pbuf[w][rt][n][qd*8];
      short8 ap1 = *(const short8*)&pbuf[w][rt][n][32+qd*8];
      #pragma unroll
      for (int dg=0; dg<4; dg++){
        o[rt][dg] = mfma16(ap0, vb[dg][0], o[rt][dg]);
        o[rt][dg] = mfma16(ap1, vb[dg][1], o[rt][dg]);
      }
    }
  }
  // epilogue: partial o (fp32), m, l
  size_t base = ((size_t)sp*(B_*H_) + bh)*M_;
  #pragma unroll
  for (int rt=0; rt<4; rt++){
    #pragma unroll
    for (int rg=0; rg<4; rg++){
      int row = r0 + rt*16 + qd*4 + rg;
      if (n==0){ MP[base+row] = mrun[rt][rg]; LP[base+row] = lrun[rt][rg]; }
      #pragma unroll
      for (int dg=0; dg<4; dg++)
        OP[(base+row)*DH_ + dg*16 + n] = o[rt][dg][rg];
    }
  }
}

// ---------------- merge NSPLIT flash partials -> kv3 ----------------
__global__ __launch_bounds__(256) void k_flash_merge(const float* __restrict__ OP,
    const float* __restrict__ MP, const float* __restrict__ LP, bf16* __restrict__ O){
  int bh = blockIdx.y;
  int r = blockIdx.x*4 + (threadIdx.x>>6);
  int dh = threadIdx.x & 63;
  float M = -1e30f, acc = 0.f, den = 0.f;
  for (int s=0; s<NSPLIT; s++){
    size_t base = ((size_t)s*(B_*H_) + bh)*M_ + r;
    float m = MP[base];
    float l = LP[base];
    float ov = OP[base*DH_ + dh];
    float Mn = fmaxf(M, m);
    float wo = __expf(M - Mn), wn = __expf(m - Mn);
    acc = acc*wo + ov*wn;
    den = den*wo + l*wn;
    M = Mn;
  }
  O[((size_t)bh*M_ + r)*DH_ + dh] = f2bf(acc/den);
}

// ---------------- attn1 flash (single-pass softmax, ncols = M_ = 256) ----------------
// Whole score row (256 cols) lives in 16 f32x4 regs: one max/exp/sum pass, no online rescale.
__global__ __launch_bounds__(256, 2) void k_flash_w2(const bf16* __restrict__ Q,
    const bf16* __restrict__ K, const bf16* __restrict__ VT, bf16* __restrict__ O){
  int bh = blockIdx.y;
  int t = threadIdx.x, w = t>>6, lane = t&63, qd = lane>>4, n = lane&15;
  int r0 = blockIdx.x*64 + w*16;
  const size_t Qoff = ((size_t)bh*N_ + r0)*DH_;
  const size_t Koff = (size_t)bh*M_*DH_;
  const size_t Voff = (size_t)bh*DH_*M_;
  __shared__ __align__(16) bf16 pbuf[4][16][264];
  short8 aq0 = *(const short8*)&Q[Qoff + (size_t)n*DH_ + qd*8];
  short8 aq1 = *(const short8*)&Q[Qoff + (size_t)n*DH_ + 32 + qd*8];
  f32x4 s[16];
  #pragma unroll
  for (int cg=0; cg<16; cg++){
    const bf16* kp = K + Koff + (size_t)(cg*16+n)*DH_;
    short8 b0 = *(const short8*)&kp[qd*8];
    short8 b1 = *(const short8*)&kp[32 + qd*8];
    f32x4 z = (f32x4){0.f,0.f,0.f,0.f};
    z = mfma16(aq0, b0, z);
    z = mfma16(aq1, b1, z);
    s[cg] = z;
  }
  float inv[4];
  #pragma unroll
  for (int rg=0; rg<4; rg++){
    float mx = s[0][rg];
    #pragma unroll
    for (int cg=1; cg<16; cg++) mx = fmaxf(mx, s[cg][rg]);
    mx = fmaxf(mx, __shfl_xor(mx, 1));
    mx = fmaxf(mx, __shfl_xor(mx, 2));
    mx = fmaxf(mx, __shfl_xor(mx, 4));
    mx = fmaxf(mx, __shfl_xor(mx, 8));
    float sum = 0.f;
    #pragma unroll
    for (int cg=0; cg<16; cg++){
      float p = __expf(s[cg][rg] - mx);
      sum += p;
      pbuf[w][qd*4+rg][cg*16+n] = f2bf(p);
    }
    sum += __shfl_xor(sum, 1);
    sum += __shfl_xor(sum, 2);
    sum += __shfl_xor(sum, 4);
    sum += __shfl_xor(sum, 8);
    inv[rg] = 1.f/sum;
  }
  f32x4 o[4];
  #pragma unroll
  for (int dg=0; dg<4; dg++) o[dg] = (f32x4){0.f,0.f,0.f,0.f};
  #pragma unroll
  for (int kc=0; kc<8; kc++){
    short8 ap = *(const short8*)&pbuf[w][n][kc*32 + qd*8];
    const bf16* vp = VT + Voff + kc*32 + qd*8;
    #pragma unroll
    for (int dg=0; dg<4; dg++){
      short8 bv = *(const short8*)&vp[(size_t)(dg*16+n)*M_];
      o[dg] = mfma16(ap, bv, o[dg]);
    }
  }
  #pragma unroll
  for (int rg=0; rg<4; rg++){
    size_t rowoff = ((size_t)bh*N_ + r0 + qd*4 + rg)*DH_;
    O[rowoff + n]      = f2bf(o[0][rg]*inv[rg]);
    O[rowoff + 16 + n] = f2bf(o[1][rg]*inv[rg]);
    O[rowoff + 32 + n] = f2bf(o[2][rg]*inv[rg]);
    O[rowoff + 48 + n] = f2bf(o[3][rg]*inv[rg]);
  }
}

// ---------------- depthwise conv(KER=33), LDS-tiled, vectorized RMW into outh ----------------
#define CCH 256
__global__ __launch_bounds__(256) void k_conv_add(const bf16* __restrict__ v, const float* __restrict__ w,
    bf16* __restrict__ outh){
  int bh = blockIdx.y;
  int n0 = blockIdx.x * CCH;
  int h = bh & 7;
  __shared__ bf16 vs[CCH+32][72];
  __shared__ float wk[KER_];
  int t = threadIdx.x;
  if (t < KER_) wk[t] = w[h*KER_ + t];
  const bf16* vb = v + (size_t)bh*N_*DH_;
  for (int i=t; i<(CCH+32)*8; i+=256){
    int r = i>>3, cg = i&7;
    int nn = n0 - 16 + r;
    short8 val = {0,0,0,0,0,0,0,0};
    if (nn >= 0 && nn < N_) val = *(const short8*)&vb[(size_t)nn*DH_ + cg*8];
    *(short8*)&vs[r][cg*8] = val;
  }
  __syncthreads();
  int dhg = t & 7, rowg = t >> 3;
  bf16* ob = outh + ((size_t)bh*N_ + n0)*DH_;
  #pragma unroll
  for (int rr=0; rr<8; rr++){
    int lr = rowg*8 + rr;
    float acc[8] = {0.f,0.f,0.f,0.f,0.f,0.f,0.f,0.f};
    for (int tt=0; tt<KER_; tt++){
      short8 vv = *(const short8*)&vs[lr+tt][dhg*8];
      float wt = wk[tt];
      #pragma unroll
      for (int j=0;j<8;j++) acc[j] += wt * bf2f(((bf16*)&vv)[j]);
    }
    short8 o = *(short8*)&ob[(size_t)lr*DH_ + dhg*8];
    #pragma unroll
    for (int j=0;j<8;j++) ((bf16*)&o)[j] = f2bf(bf2f(((bf16*)&o)[j]) + acc[j]);
    *(short8*)&ob[(size_t)lr*DH_ + dhg*8] = o;
  }
}

// ---------------- final GEMM (MFMA, LDS-staged): out = x + gather(outh) @ WT2^T + b_out ----------------
__global__ __launch_bounds__(256) void k_mm_out2(const bf16* __restrict__ Ahd, const bf16* __restrict__ WT2,
    const float* __restrict__ bias, const float* __restrict__ xin, float* __restrict__ out){
  __shared__ __align__(16) bf16 As[128][72];
  __shared__ __align__(16) bf16 Bs[128][72];
  int t = threadIdx.x;
  int w = t>>6, lane = t&63, qd = lane>>4, n = lane&15;
  int wm = w>>1, wn = w&1;
  int r0 = blockIdx.x*128, c0 = blockIdx.y*128;
  f32x4 acc[4][4];
  #pragma unroll
  for (int i=0;i<4;i++)
    #pragma unroll
    for (int j=0;j<4;j++) acc[i][j] = (f32x4){0.f,0.f,0.f,0.f};
  int srow = t>>3, skc = t&7;
  for (int k0=0; k0<512; k0+=64){
    int h = k0 >> 6;
    #pragma unroll
    for (int ch=0; ch<4; ch++){
      int m = ch*32 + srow;
      int r = r0 + m, b = r>>13, nn = r&8191;
      *(short8*)&As[m][skc*8] = *(const short8*)&Ahd[((size_t)(b*H_+h)*N_ + nn)*DH_ + skc*8];
      *(short8*)&Bs[m][skc*8] = *(const short8*)&WT2[(size_t)(c0+m)*512 + k0 + skc*8];
    }
    __syncthreads();
    #pragma unroll
    for (int ksub=0; ksub<2; ksub++){
      short8 af[4], bfr[4];
      #pragma unroll
      for (int i=0;i<4;i++) af[i]  = *(const short8*)&As[wm*64+i*16+n][ksub*32+qd*8];
      #pragma unroll
      for (int j=0;j<4;j++) bfr[j] = *(const short8*)&Bs[wn*64+j*16+n][ksub*32+qd*8];
      #pragma unroll
      for (int i=0;i<4;i++)
        #pragma unroll
        for (int j=0;j<4;j++) acc[i][j] = mfma16(af[i], bfr[j], acc[i][j]);
    }
    __syncthreads();
  }
  #pragma unroll
  for (int i=0;i<4;i++){
    #pragma unroll
    for (int j=0;j<4;j++){
      int c = c0 + wn*64 + j*16 + n;
      #pragma unroll
      for (int rg=0; rg<4; rg++){
        int r = r0 + wm*64 + i*16 + qd*4 + rg;
        out[(size_t)r*512 + c] = acc[i][j][rg] + bias[c] + xin[(size_t)r*512 + c];
      }
    }
  }
}

extern "C" void kernel_launch(void* const* d_in, const int* in_sizes, int n_in,
                              void* d_out, int out_size, void* d_ws, size_t ws_size,
                              hipStream_t stream) {
  const float* x     = (const float*)d_in[0];
  const float* gamma = (const float*)d_in[1];
  const float* beta  = (const float*)d_in[2];
  const float* wqkv  = (const float*)d_in[3];
  const float* resk  = (const float*)d_in[4];
  const float* wout  = (const float*)d_in[5];
  const float* bout  = (const float*)d_in[6];
  float* out = (float*)d_out;

  const size_t SL = (size_t)B_*H_*N_*DH_;
  const size_t SM = (size_t)B_*H_*M_*DH_;
  const size_t SP = (size_t)B_*H_*M_*M_;

  bf16* xn  = (bf16*)d_ws;     // reused as: flash partial OP, then pinv P1..P4, then outh
  bf16* q   = xn + SL;
  bf16* k   = q + SL;
  bf16* v   = k + SL;
  bf16* vT  = v + SL;
  bf16* ql  = vT + SL;
  bf16* kl  = ql + SM;
  bf16* kv3 = kl + SM;
  bf16* z2T = kv3 + SM;
  float* A2 = (float*)(z2T + SM);
  bf16* WT  = (bf16*)(A2 + SP);       // 1536 x 512 bf16
  bf16* WT2 = WT + (size_t)1536*512;  // 512 x 512 bf16
  float* P1 = (float*)xn;             // pinv scratch aliases xn (4*SP*4B == SL*2B)
  float* P2 = P1 + SP;
  float* P3 = P2 + SP;
  float* P4 = P3 + SP;
  // flash-decoding partials: OP aliases xn region (NSPLIT*32*256*64*4B == SL*2B exactly);
  // MP/LP alias z2T region (2*NSPLIT*32*256*4B == SM*2B exactly). Both dead before reuse.
  float* OPp = (float*)xn;
  float* MPp = (float*)z2T;
  float* LPp = MPp + (size_t)NSPLIT*B_*H_*M_;

  k_wt<<<dim3(24, 8), 256, 0, stream>>>(wqkv, WT, 512, 1536);
  k_wt<<<dim3(8, 8), 256, 0, stream>>>(wout, WT2, 512, 512);
  k_layernorm<<<B_*N_, 256, 0, stream>>>(x, gamma, beta, xn);
  k_mm_qkv2<<<dim3(256, 12), 256, 0, stream>>>(xn, WT, q, k, v);
  k_transp_v<<<dim3(128, 32), 256, 0, stream>>>(v, vT);
  k_landmark<<<B_*H_*M_, 64, 0, stream>>>(q, k, ql, kl);

  // attn3 flash (split + merge) runs BEFORE pinv so partials can use the dead xn/z2T regions
  k_flash_split<<<dim3(NSPLIT, B_*H_), 256, 0, stream>>>(ql, k, vT, OPp, MPp, LPp);
  k_flash_merge<<<dim3(M_/4, B_*H_), 256, 0, stream>>>(OPp, MPp, LPp, kv3);

  k_attn2<<<B_*H_*M_, 256, 0, stream>>>(ql, kl, A2);
  k_pinv_init<<<B_*H_, 256, 0, stream>>>(A2, P1);

  float* Zi = P1; float* Zo = P3;
  for (int it=0; it<6; ++it){
    k_gemm_pm<<<dim3(16,32), 256, 0, stream>>>(P2, A2, Zi, 0.f,0, 0.f,0, 1.f);    // P = A2@Z
    k_gemm_pm<<<dim3(16,32), 256, 0, stream>>>(Zo, P2, P2, 7.f,1, 15.f,1, 1.f);   // S = 15I - P@(7I-P)
    k_gemm_pm<<<dim3(16,32), 256, 0, stream>>>(P4, P2, Zo, 0.f,0, 13.f,1, 1.f);   // U = 13I - P@S
    k_gemm_pm<<<dim3(16,32), 256, 0, stream>>>(Zo, Zi, P4, 0.f,0, 0.f,0, 0.25f);  // Zn = 0.25*Z@U
    float* tt = Zi; Zi = Zo; Zo = tt;
  }

  k_gemm_z2<<<dim3(4, B_*H_), 256, 0, stream>>>(z2T, Zi, kv3);
  k_flash_w2<<<dim3(N_/64, B_*H_), 256, 0, stream>>>(q, kl, z2T, xn);
  k_conv_add<<<dim3(N_/CCH, B_*H_), 256, 0, stream>>>(v, resk, xn);
  k_mm_out2<<<dim3(256, 4), 256, 0, stream>>>(xn, WT2, bout, x, out);
}

// Round 2
// 925.522 us; speedup vs baseline: 1.1633x; 1.1204x over previous
//
#include <hip/hip_runtime.h>
#include <hip/hip_bf16.h>

#define B_ 4
#define N_ 8192
#define D_ 512
#define H_ 8
#define DH_ 64
#define M_ 256
#define LCH 32
#define KER_ 33
#define NSPLIT 16
#define CS (N_/NSPLIT)   // 512 cols per split chunk

typedef __hip_bfloat16 bf16;
typedef __attribute__((ext_vector_type(8))) short short8;
typedef __attribute__((ext_vector_type(4))) float f32x4;

__device__ __forceinline__ float bf2f(bf16 h){ return __bfloat162float(h); }
__device__ __forceinline__ bf16 f2bf(float f){ return __float2bfloat16(f); }
__device__ __forceinline__ f32x4 mfma16(short8 a, short8 b, f32x4 c){
  return __builtin_amdgcn_mfma_f32_16x16x32_bf16(a, b, c, 0, 0, 0);
}

// ---------------- LayerNorm: x (b,n,512) fp32 -> xn bf16 ----------------
__global__ __launch_bounds__(256) void k_layernorm(const float* __restrict__ x,
    const float* __restrict__ gamma, const float* __restrict__ beta,
    bf16* __restrict__ xn){
  int row = blockIdx.x;
  const float* xr = x + (size_t)row * D_;
  bf16* o = xn + (size_t)row * D_;
  int t = threadIdx.x;
  float v0 = xr[t], v1 = xr[t+256];
  float s = v0+v1, ss = v0*v0 + v1*v1;
  __shared__ float sh[8];
  for (int off=32; off; off>>=1){ s += __shfl_xor(s,off); ss += __shfl_xor(ss,off); }
  int lane = t&63, wid = t>>6;
  if (lane==0){ sh[wid] = s; sh[wid+4] = ss; }
  __syncthreads();
  float S  = sh[0]+sh[1]+sh[2]+sh[3];
  float SS = sh[4]+sh[5]+sh[6]+sh[7];
  float mu = S*(1.f/D_);
  float var = SS*(1.f/D_) - mu*mu;
  float rs = rsqrtf(var + 1e-5f);
  o[t]     = f2bf((v0-mu)*rs*gamma[t]     + beta[t]);
  o[t+256] = f2bf((v1-mu)*rs*gamma[t+256] + beta[t+256]);
}

// ---------------- W transpose+convert: W (RxC fp32) -> WT (CxR bf16) ----------------
__global__ __launch_bounds__(256) void k_wt(const float* __restrict__ W, bf16* __restrict__ WT,
    int R, int C){
  int c0 = blockIdx.x*64, r0 = blockIdx.y*64;
  __shared__ float tile[64][65];
  int t = threadIdx.x;
  for (int i=t;i<4096;i+=256){ int r=i>>6, c=i&63; tile[r][c] = W[(size_t)(r0+r)*C + c0+c]; }
  __syncthreads();
  for (int i=t;i<512;i+=256){
    int c=i>>3, rg=i&7;
    short8 o;
    #pragma unroll
    for (int j=0;j<8;j++) ((bf16*)&o)[j] = f2bf(tile[rg*8+j][c]);
    *(short8*)&WT[(size_t)(c0+c)*R + r0 + rg*8] = o;
  }
}

// ---------------- QKV GEMM (MFMA, LDS-staged 128x128 tile): xn @ WT^T -> q,k,v ----------------
__global__ __launch_bounds__(256) void k_mm_qkv2(const bf16* __restrict__ A, const bf16* __restrict__ WT,
    bf16* __restrict__ qbuf, bf16* __restrict__ kbuf, bf16* __restrict__ vbuf){
  __shared__ __align__(16) bf16 As[128][72];
  __shared__ __align__(16) bf16 Bs[128][72];
  int t = threadIdx.x;
  int w = t>>6, lane = t&63, qd = lane>>4, n = lane&15;
  int wm = w>>1, wn = w&1;
  int r0 = blockIdx.x*128, c0 = blockIdx.y*128;
  f32x4 acc[4][4];
  #pragma unroll
  for (int i=0;i<4;i++)
    #pragma unroll
    for (int j=0;j<4;j++) acc[i][j] = (f32x4){0.f,0.f,0.f,0.f};
  int srow = t>>3, skc = t&7;
  for (int k0=0; k0<512; k0+=64){
    #pragma unroll
    for (int ch=0; ch<4; ch++){
      int m = ch*32 + srow;
      *(short8*)&As[m][skc*8] = *(const short8*)&A[(size_t)(r0+m)*512 + k0 + skc*8];
      *(short8*)&Bs[m][skc*8] = *(const short8*)&WT[(size_t)(c0+m)*512 + k0 + skc*8];
    }
    __syncthreads();
    #pragma unroll
    for (int ksub=0; ksub<2; ksub++){
      short8 af[4], bfr[4];
      #pragma unroll
      for (int i=0;i<4;i++) af[i]  = *(const short8*)&As[wm*64+i*16+n][ksub*32+qd*8];
      #pragma unroll
      for (int j=0;j<4;j++) bfr[j] = *(const short8*)&Bs[wn*64+j*16+n][ksub*32+qd*8];
      #pragma unroll
      for (int i=0;i<4;i++)
        #pragma unroll
        for (int j=0;j<4;j++) acc[i][j] = mfma16(af[i], bfr[j], acc[i][j]);
    }
    __syncthreads();
  }
  int part = c0 >> 9;
  bf16* dst = (part==0)? qbuf : (part==1)? kbuf : vbuf;
  float scale = (part==0)? 0.125f : 1.f;
  #pragma unroll
  for (int i=0;i<4;i++){
    #pragma unroll
    for (int j=0;j<4;j++){
      int c = c0 + wn*64 + j*16 + n;
      int cc = c & 511, h = cc>>6, dh = cc&63;
      #pragma unroll
      for (int rg=0; rg<4; rg++){
        int r = r0 + wm*64 + i*16 + qd*4 + rg;
        int b = r >> 13, nn = r & 8191;
        dst[(((size_t)(b*H_+h))*N_ + nn)*DH_ + dh] = f2bf(acc[i][j][rg]*scale);
      }
    }
  }
}

// ---------------- v -> vT tiled transpose (64x64) ----------------
__global__ __launch_bounds__(256) void k_transp_v(const bf16* __restrict__ v, bf16* __restrict__ vT){
  int bh = blockIdx.y, n0 = blockIdx.x*64;
  __shared__ bf16 tile[64][72];
  const bf16* vb = v + (size_t)bh*N_*DH_;
  int t = threadIdx.x;
  for (int i=t; i<512; i+=256){
    int r = i>>3, cg = i&7;
    *(short8*)&tile[r][cg*8] = *(const short8*)&vb[(size_t)(n0+r)*DH_ + cg*8];
  }
  __syncthreads();
  bf16* ob = vT + (size_t)bh*DH_*N_;
  for (int i=t; i<512; i+=256){
    int dh = i>>3, ng = i&7;
    short8 o;
    #pragma unroll
    for (int j=0;j<8;j++) ((bf16*)&o)[j] = tile[ng*8+j][dh];
    *(short8*)&ob[(size_t)dh*N_ + n0 + ng*8] = o;
  }
}

// ---------------- landmark means over contiguous 32-row chunks ----------------
__global__ __launch_bounds__(64) void k_landmark(const bf16* __restrict__ q, const bf16* __restrict__ k,
    bf16* __restrict__ ql, bf16* __restrict__ kl){
  int bhm = blockIdx.x;
  int bh = bhm >> 8, m = bhm & 255;
  int dh = threadIdx.x;
  const bf16* qp = q + ((size_t)bh*N_ + (size_t)m*LCH)*DH_ + dh;
  const bf16* kp = k + ((size_t)bh*N_ + (size_t)m*LCH)*DH_ + dh;
  float sq=0.f, sk=0.f;
  #pragma unroll
  for (int j=0;j<LCH;j++){ sq += bf2f(qp[(size_t)j*DH_]); sk += bf2f(kp[(size_t)j*DH_]); }
  ql[((size_t)bh*M_ + m)*DH_ + dh] = f2bf(sq*(1.f/LCH));
  kl[((size_t)bh*M_ + m)*DH_ + dh] = f2bf(sk*(1.f/LCH));
}

// ---------------- attn2 = softmax(q_l @ k_l^T) rows (fp32 out) ----------------
__global__ __launch_bounds__(256) void k_attn2(const bf16* __restrict__ ql, const bf16* __restrict__ kl,
    float* __restrict__ A2){
  int bhm = blockIdx.x;
  int bh = bhm >> 8, m = bhm & 255;
  int t = threadIdx.x;
  __shared__ float qrow[64];
  __shared__ float sh[4];
  if (t < 64) qrow[t] = bf2f(ql[((size_t)bh*M_ + m)*DH_ + t]);
  __syncthreads();
  const bf16* krow = kl + ((size_t)bh*M_ + t)*DH_;
  float s = 0.f;
  #pragma unroll
  for (int i=0;i<64;i++) s += qrow[i]*bf2f(krow[i]);
  float mx = s;
  for (int off=32; off; off>>=1) mx = fmaxf(mx, __shfl_xor(mx, off));
  if ((t&63)==0) sh[t>>6] = mx;
  __syncthreads();
  mx = fmaxf(fmaxf(sh[0],sh[1]), fmaxf(sh[2],sh[3]));
  float e = expf(s - mx);
  float sum = e;
  for (int off=32; off; off>>=1) sum += __shfl_xor(sum, off);
  __syncthreads();
  if ((t&63)==0) sh[t>>6] = sum;
  __syncthreads();
  sum = sh[0]+sh[1]+sh[2]+sh[3];
  A2[((size_t)bh*M_ + m)*M_ + t] = e/sum;
}

// ---------------- pinv init: Z = A^T / (max_rowsum * max_colsum) ----------------
__global__ __launch_bounds__(256) void k_pinv_init(const float* __restrict__ A2, float* __restrict__ Z){
  int bh = blockIdx.x;
  int t = threadIdx.x;
  const float* Ab = A2 + (size_t)bh*M_*M_;
  float* Zb = Z + (size_t)bh*M_*M_;
  float cs=0.f, rsm=0.f;
  for (int r=0;r<M_;r++) cs += fabsf(Ab[(size_t)r*M_ + t]);
  for (int c=0;c<M_;c++) rsm += fabsf(Ab[(size_t)t*M_ + c]);
  __shared__ float sh[4];
  float v = cs;
  for (int off=32; off; off>>=1) v = fmaxf(v, __shfl_xor(v, off));
  if ((t&63)==0) sh[t>>6] = v;
  __syncthreads();
  float maxc = fmaxf(fmaxf(sh[0],sh[1]), fmaxf(sh[2],sh[3]));
  __syncthreads();
  v = rsm;
  for (int off=32; off; off>>=1) v = fmaxf(v, __shfl_xor(v, off));
  if ((t&63)==0) sh[t>>6] = v;
  __syncthreads();
  float maxr = fmaxf(fmaxf(sh[0],sh[1]), fmaxf(sh[2],sh[3]));
  float inv = 1.f/(maxr*maxc);
  for (int r=0;r<M_;r++) Zb[(size_t)r*M_ + t] = Ab[(size_t)t*M_ + r]*inv;
}

// ---------------- pinv GEMM (bf16 MFMA; optional hi/lo split precision) ----------------
// C = cScale*(cNeg? cDiag*I - A@B' : A@B'), B' = bNeg? bDiag*I-B : B
// split=1: 3 MFMAs/product (fp32-grade). split=0: 1 MFMA/product (plain bf16, for early
// Newton-Schulz iterations where errors are self-corrected by later split iterations).
__global__ __launch_bounds__(256) void k_gemm_pm(float* __restrict__ C, const float* __restrict__ A,
    const float* __restrict__ Bm, float bDiag, int bNeg, float cDiag, int cNeg, float cScale,
    int split){
  int bh = blockIdx.y;
  int tm = blockIdx.x >> 2, tn = blockIdx.x & 3;
  const float* Ab = A  + (size_t)bh*65536;
  const float* Bb = Bm + (size_t)bh*65536;
  float* Cb = C + (size_t)bh*65536;
  __shared__ __align__(16) bf16 Ah[64][72];
  __shared__ __align__(16) bf16 Al[64][72];
  __shared__ __align__(16) bf16 Bh[64][72];
  __shared__ __align__(16) bf16 Bl[64][72];
  int t = threadIdx.x;
  int w = t>>6, lane = t&63, qd = lane>>4, n = lane&15;
  int wm = w>>1, wn = w&1;
  int r0 = tm*64, c0 = tn*64;
  f32x4 acc[2][2];
  #pragma unroll
  for (int i=0;i<2;i++)
    #pragma unroll
    for (int j=0;j<2;j++) acc[i][j] = (f32x4){0.f,0.f,0.f,0.f};
  int srow = t>>3, skc = t&7;
  for (int k0=0; k0<256; k0+=64){
    #pragma unroll
    for (int ch=0; ch<2; ch++){
      int m = ch*32 + srow;
      short8 vh, vl;
      const float* ap = &Ab[(size_t)(r0+m)*256 + k0 + skc*8];
      #pragma unroll
      for (int j=0;j<8;j++){
        float x = ap[j];
        bf16 h = f2bf(x);
        ((bf16*)&vh)[j] = h;
        if (split) ((bf16*)&vl)[j] = f2bf(x - bf2f(h));
      }
      *(short8*)&Ah[m][skc*8] = vh;
      if (split) *(short8*)&Al[m][skc*8] = vl;
      const float* bp = &Bb[(size_t)(k0+m)*256 + c0 + skc*8];
      int kr = k0 + m;
      #pragma unroll
      for (int j=0;j<8;j++){
        float x = bp[j];
        if (bNeg) x = (kr == (c0 + skc*8 + j) ? bDiag : 0.f) - x;
        bf16 h = f2bf(x);
        ((bf16*)&vh)[j] = h;
        if (split) ((bf16*)&vl)[j] = f2bf(x - bf2f(h));
      }
      #pragma unroll
      for (int j=0;j<8;j++){
        Bh[skc*8+j][m] = ((bf16*)&vh)[j];
        if (split) Bl[skc*8+j][m] = ((bf16*)&vl)[j];
      }
    }
    __syncthreads();
    #pragma unroll
    for (int ksub=0; ksub<2; ksub++){
      short8 afh[2], afl[2], bfh[2], bfl[2];
      #pragma unroll
      for (int i=0;i<2;i++){
        afh[i] = *(const short8*)&Ah[wm*32+i*16+n][ksub*32+qd*8];
        if (split) afl[i] = *(const short8*)&Al[wm*32+i*16+n][ksub*32+qd*8];
      }
      #pragma unroll
      for (int j=0;j<2;j++){
        bfh[j] = *(const short8*)&Bh[wn*32+j*16+n][ksub*32+qd*8];
        if (split) bfl[j] = *(const short8*)&Bl[wn*32+j*16+n][ksub*32+qd*8];
      }
      #pragma unroll
      for (int i=0;i<2;i++)
        #pragma unroll
        for (int j=0;j<2;j++){
          if (split){
            acc[i][j] = mfma16(afl[i], bfh[j], acc[i][j]);
            acc[i][j] = mfma16(afh[i], bfl[j], acc[i][j]);
          }
          acc[i][j] = mfma16(afh[i], bfh[j], acc[i][j]);
        }
    }
    __syncthreads();
  }
  #pragma unroll
  for (int i=0;i<2;i++){
    #pragma unroll
    for (int j=0;j<2;j++){
      int cidx = c0 + wn*32 + j*16 + n;
      #pragma unroll
      for (int rg=0; rg<4; rg++){
        int r = r0 + wm*32 + i*16 + qd*4 + rg;
        float r_ = acc[i][j][rg];
        if (cNeg) r_ = ((r==cidx)? cDiag : 0.f) - r_;
        Cb[(size_t)r*256 + cidx] = r_*cScale;
      }
    }
  }
}

// ---------------- batched GEMM 256x64x256: z2T = (Z @ kv3)^T ----------------
__global__ __launch_bounds__(256) void k_gemm_z2(bf16* __restrict__ z2t, const float* __restrict__ A,
    const bf16* __restrict__ Bm){
  int bh = blockIdx.y;
  int tm = blockIdx.x;
  const float* Ab = A  + (size_t)bh*65536;
  const bf16* Bb = Bm + (size_t)bh*M_*DH_;
  __shared__ float As[16][68];
  __shared__ float Bs[16][64];
  int t = threadIdx.x, tx = t&15, ty = t>>4;
  int r0 = tm*64;
  float acc[4][4] = {};
  for (int k0=0;k0<256;k0+=16){
    for (int i=t;i<1024;i+=256){
      int m=i>>4, kq=i&15;
      As[kq][m] = Ab[(size_t)(r0+m)*256 + k0+kq];
      int nn=i&63, k2=i>>6;
      Bs[k2][nn] = bf2f(Bb[(size_t)(k0+k2)*64 + nn]);
    }
    __syncthreads();
    #pragma unroll
    for (int kq=0;kq<16;kq++){
      float a0[4], b0[4];
      #pragma unroll
      for (int i=0;i<4;i++) a0[i] = As[kq][ty*4+i];
      #pragma unroll
      for (int j=0;j<4;j++) b0[j] = Bs[kq][tx*4+j];
      #pragma unroll
      for (int i=0;i<4;i++)
        #pragma unroll
        for (int j=0;j<4;j++) acc[i][j] += a0[i]*b0[j];
    }
    __syncthreads();
  }
  #pragma unroll
  for (int i=0;i<4;i++){
    int r = r0+ty*4+i;
    #pragma unroll
    for (int j=0;j<4;j++)
      z2t[(size_t)bh*16384 + (size_t)(tx*4+j)*256 + r] = f2bf(acc[i][j]);
  }
}

// ---------------- attn3 flash, flash-decoding split over columns ----------------
__global__ __launch_bounds__(256, 2) void k_flash_split(const bf16* __restrict__ Q,
    const bf16* __restrict__ K, const bf16* __restrict__ VT,
    float* __restrict__ OP, float* __restrict__ MP, float* __restrict__ LP){
  int bh = blockIdx.y;
  int sp = blockIdx.x;
  int t = threadIdx.x, w = t>>6, lane = t&63, qd = lane>>4, n = lane&15;
  int r0 = w*64;
  const size_t Qoff = ((size_t)bh*M_ + r0)*DH_;
  const size_t Koff = ((size_t)bh*N_ + (size_t)sp*CS)*DH_;
  const size_t Voff = (size_t)bh*DH_*N_ + (size_t)sp*CS;
  __shared__ __align__(16) bf16 pbuf[4][4][16][72];
  short8 aq[4][2];
  #pragma unroll
  for (int rt=0; rt<4; rt++){
    aq[rt][0] = *(const short8*)&Q[Qoff + (size_t)(rt*16+n)*DH_ + qd*8];
    aq[rt][1] = *(const short8*)&Q[Qoff + (size_t)(rt*16+n)*DH_ + 32 + qd*8];
  }
  f32x4 o[4][4];
  float mrun[4][4], lrun[4][4];
  #pragma unroll
  for (int rt=0; rt<4; rt++){
    #pragma unroll
    for (int j=0;j<4;j++){ o[rt][j] = (f32x4){0.f,0.f,0.f,0.f}; mrun[rt][j] = -1e30f; lrun[rt][j] = 0.f; }
  }
  for (int tl=0; tl<CS/64; ++tl){
    const bf16* kp = K + Koff + (size_t)(tl*64)*DH_;
    short8 kb[4][2];
    #pragma unroll
    for (int cg=0; cg<4; cg++){
      kb[cg][0] = *(const short8*)&kp[(size_t)(cg*16+n)*DH_ + qd*8];
      kb[cg][1] = *(const short8*)&kp[(size_t)(cg*16+n)*DH_ + 32 + qd*8];
    }
    #pragma unroll
    for (int rt=0; rt<4; rt++){
      f32x4 s[4];
      #pragma unroll
      for (int cg=0; cg<4; cg++){
        f32x4 z = (f32x4){0.f,0.f,0.f,0.f};
        z = mfma16(aq[rt][0], kb[cg][0], z);
        z = mfma16(aq[rt][1], kb[cg][1], z);
        s[cg] = z;
      }
      float alpha[4];
      #pragma unroll
      for (int rg=0; rg<4; rg++){
        float smax = fmaxf(fmaxf(s[0][rg],s[1][rg]), fmaxf(s[2][rg],s[3][rg]));
        smax = fmaxf(smax, __shfl_xor(smax, 1));
        smax = fmaxf(smax, __shfl_xor(smax, 2));
        smax = fmaxf(smax, __shfl_xor(smax, 4));
        smax = fmaxf(smax, __shfl_xor(smax, 8));
        float mn = fmaxf(mrun[rt][rg], smax);
        float p0 = __expf(s[0][rg]-mn), p1 = __expf(s[1][rg]-mn);
        float p2 = __expf(s[2][rg]-mn), p3 = __expf(s[3][rg]-mn);
        float ts = p0+p1+p2+p3;
        ts += __shfl_xor(ts,1); ts += __shfl_xor(ts,2);
        ts += __shfl_xor(ts,4); ts += __shfl_xor(ts,8);
        float al = __expf(mrun[rt][rg]-mn);
        lrun[rt][rg] = lrun[rt][rg]*al + ts;
        mrun[rt][rg] = mn;
        alpha[rg] = al;
        pbuf[w][rt][qd*4+rg][n]    = f2bf(p0);
        pbuf[w][rt][qd*4+rg][16+n] = f2bf(p1);
        pbuf[w][rt][qd*4+rg][32+n] = f2bf(p2);
        pbuf[w][rt][qd*4+rg][48+n] = f2bf(p3);
      }
      #pragma unroll
      for (int dg=0; dg<4; dg++)
        #pragma unroll
        for (int rg=0; rg<4; rg++) o[rt][dg][rg] *= alpha[rg];
    }
    const bf16* vp = VT + Voff + tl*64 + qd*8;
    short8 vb[4][2];
    #pragma unroll
    for (int dg=0; dg<4; dg++){
      vb[dg][0] = *(const short8*)&vp[(size_t)(dg*16+n)*N_];
      vb[dg][1] = *(const short8*)&vp[(size_t)(dg*16+n)*N_ + 32];
    }
    #pragma unroll
    for (int rt=0; rt<4; rt++){
      short8 ap0 = *(const short8*)&pbuf[w][rt][n][qd*8];
      short8 ap1 = *(const short8*)&pbuf[w][rt][n][32+qd*8];
      #pragma unroll
      for (int dg=0; dg<4; dg++){
        o[rt][dg] = mfma16(ap0, vb[dg][0], o[rt][dg]);
        o[rt][dg] = mfma16(ap1, vb[dg][1], o[rt][dg]);
      }
    }
  }
  size_t base = ((size_t)sp*(B_*H_) + bh)*M_;
  #pragma unroll
  for (int rt=0; rt<4; rt++){
    #pragma unroll
    for (int rg=0; rg<4; rg++){
      int row = r0 + rt*16 + qd*4 + rg;
      if (n==0){ MP[base+row] = mrun[rt][rg]; LP[base+row] = lrun[rt][rg]; }
      #pragma unroll
      for (int dg=0; dg<4; dg++)
        OP[(base+row)*DH_ + dg*16 + n] = o[rt][dg][rg];
    }
  }
}

// ---------------- merge NSPLIT flash partials -> kv3 ----------------
__global__ __launch_bounds__(256) void k_flash_merge(const float* __restrict__ OP,
    const float* __restrict__ MP, const float* __restrict__ LP, bf16* __restrict__ O){
  int bh = blockIdx.y;
  int r = blockIdx.x*4 + (threadIdx.x>>6);
  int dh = threadIdx.x & 63;
  float M = -1e30f, acc = 0.f, den = 0.f;
  for (int s=0; s<NSPLIT; s++){
    size_t base = ((size_t)s*(B_*H_) + bh)*M_ + r;
    float m = MP[base];
    float l = LP[base];
    float ov = OP[base*DH_ + dh];
    float Mn = fmaxf(M, m);
    float wo = __expf(M - Mn), wn = __expf(m - Mn);
    acc = acc*wo + ov*wn;
    den = den*wo + l*wn;
    M = Mn;
  }
  O[((size_t)bh*M_ + r)*DH_ + dh] = f2bf(acc/den);
}

// ---------------- attn1 flash, split-structured: 4 waves x 4 rowtiles, 64-col tiles ----------------
// Grid (N_/256, B*H). Wave w owns rows blockIdx.x*256 + w*64 .. +63 (4 rowtiles of 16).
// All 256 landmark cols scanned in 4 tiles of 64 with online softmax; output normalized directly.
__global__ __launch_bounds__(256, 2) void k_flash_w3(const bf16* __restrict__ Q,
    const bf16* __restrict__ K, const bf16* __restrict__ VT, bf16* __restrict__ O){
  int bh = blockIdx.y;
  int t = threadIdx.x, w = t>>6, lane = t&63, qd = lane>>4, n = lane&15;
  int r0 = blockIdx.x*256 + w*64;
  const size_t Qoff = ((size_t)bh*N_ + r0)*DH_;
  const size_t Koff = (size_t)bh*M_*DH_;
  const size_t Voff = (size_t)bh*DH_*M_;
  __shared__ __align__(16) bf16 pbuf[4][4][16][72];
  short8 aq[4][2];
  #pragma unroll
  for (int rt=0; rt<4; rt++){
    aq[rt][0] = *(const short8*)&Q[Qoff + (size_t)(rt*16+n)*DH_ + qd*8];
    aq[rt][1] = *(const short8*)&Q[Qoff + (size_t)(rt*16+n)*DH_ + 32 + qd*8];
  }
  f32x4 o[4][4];
  float mrun[4][4], lrun[4][4];
  #pragma unroll
  for (int rt=0; rt<4; rt++){
    #pragma unroll
    for (int j=0;j<4;j++){ o[rt][j] = (f32x4){0.f,0.f,0.f,0.f}; mrun[rt][j] = -1e30f; lrun[rt][j] = 0.f; }
  }
  #pragma unroll
  for (int tl=0; tl<4; ++tl){
    const bf16* kp = K + Koff + (size_t)(tl*64)*DH_;
    short8 kb[4][2];
    #pragma unroll
    for (int cg=0; cg<4; cg++){
      kb[cg][0] = *(const short8*)&kp[(size_t)(cg*16+n)*DH_ + qd*8];
      kb[cg][1] = *(const short8*)&kp[(size_t)(cg*16+n)*DH_ + 32 + qd*8];
    }
    #pragma unroll
    for (int rt=0; rt<4; rt++){
      f32x4 s[4];
      #pragma unroll
      for (int cg=0; cg<4; cg++){
        f32x4 z = (f32x4){0.f,0.f,0.f,0.f};
        z = mfma16(aq[rt][0], kb[cg][0], z);
        z = mfma16(aq[rt][1], kb[cg][1], z);
        s[cg] = z;
      }
      float alpha[4];
      #pragma unroll
      for (int rg=0; rg<4; rg++){
        float smax = fmaxf(fmaxf(s[0][rg],s[1][rg]), fmaxf(s[2][rg],s[3][rg]));
        smax = fmaxf(smax, __shfl_xor(smax, 1));
        smax = fmaxf(smax, __shfl_xor(smax, 2));
        smax = fmaxf(smax, __shfl_xor(smax, 4));
        smax = fmaxf(smax, __shfl_xor(smax, 8));
        float mn = fmaxf(mrun[rt][rg], smax);
        float p0 = __expf(s[0][rg]-mn), p1 = __expf(s[1][rg]-mn);
        float p2 = __expf(s[2][rg]-mn), p3 = __expf(s[3][rg]-mn);
        float ts = p0+p1+p2+p3;
        ts += __shfl_xor(ts,1); ts += __shfl_xor(ts,2);
        ts += __shfl_xor(ts,4); ts += __shfl_xor(ts,8);
        float al = __expf(mrun[rt][rg]-mn);
        lrun[rt][rg] = lrun[rt][rg]*al + ts;
        mrun[rt][rg] = mn;
        alpha[rg] = al;
        pbuf[w][rt][qd*4+rg][n]    = f2bf(p0);
        pbuf[w][rt][qd*4+rg][16+n] = f2bf(p1);
        pbuf[w][rt][qd*4+rg][32+n] = f2bf(p2);
        pbuf[w][rt][qd*4+rg][48+n] = f2bf(p3);
      }
      #pragma unroll
      for (int dg=0; dg<4; dg++)
        #pragma unroll
        for (int rg=0; rg<4; rg++) o[rt][dg][rg] *= alpha[rg];
    }
    const bf16* vp = VT + Voff + tl*64 + qd*8;
    short8 vb[4][2];
    #pragma unroll
    for (int dg=0; dg<4; dg++){
      vb[dg][0] = *(const short8*)&vp[(size_t)(dg*16+n)*M_];
      vb[dg][1] = *(const short8*)&vp[(size_t)(dg*16+n)*M_ + 32];
    }
    #pragma unroll
    for (int rt=0; rt<4; rt++){
      short8 ap0 = *(const short8*)&pbuf[w][rt][n][qd*8];
      short8 ap1 = *(const short8*)&pbuf[w][rt][n][32+qd*8];
      #pragma unroll
      for (int dg=0; dg<4; dg++){
        o[rt][dg] = mfma16(ap0, vb[dg][0], o[rt][dg]);
        o[rt][dg] = mfma16(ap1, vb[dg][1], o[rt][dg]);
      }
    }
  }
  #pragma unroll
  for (int rt=0; rt<4; rt++){
    #pragma unroll
    for (int rg=0; rg<4; rg++){
      float inv = 1.f/lrun[rt][rg];
      size_t rowoff = ((size_t)bh*N_ + r0 + rt*16 + qd*4 + rg)*DH_;
      #pragma unroll
      for (int dg=0; dg<4; dg++)
        O[rowoff + dg*16 + n] = f2bf(o[rt][dg][rg]*inv);
    }
  }
}

// ---------------- depthwise conv(KER=33), LDS-tiled, vectorized RMW into outh ----------------
#define CCH 256
__global__ __launch_bounds__(256) void k_conv_add(const bf16* __restrict__ v, const float* __restrict__ w,
    bf16* __restrict__ outh){
  int bh = blockIdx.y;
  int n0 = blockIdx.x * CCH;
  int h = bh & 7;
  __shared__ bf16 vs[CCH+32][72];
  __shared__ float wk[KER_];
  int t = threadIdx.x;
  if (t < KER_) wk[t] = w[h*KER_ + t];
  const bf16* vb = v + (size_t)bh*N_*DH_;
  for (int i=t; i<(CCH+32)*8; i+=256){
    int r = i>>3, cg = i&7;
    int nn = n0 - 16 + r;
    short8 val = {0,0,0,0,0,0,0,0};
    if (nn >= 0 && nn < N_) val = *(const short8*)&vb[(size_t)nn*DH_ + cg*8];
    *(short8*)&vs[r][cg*8] = val;
  }
  __syncthreads();
  int dhg = t & 7, rowg = t >> 3;
  bf16* ob = outh + ((size_t)bh*N_ + n0)*DH_;
  #pragma unroll
  for (int rr=0; rr<8; rr++){
    int lr = rowg*8 + rr;
    float acc[8] = {0.f,0.f,0.f,0.f,0.f,0.f,0.f,0.f};
    for (int tt=0; tt<KER_; tt++){
      short8 vv = *(const short8*)&vs[lr+tt][dhg*8];
      float wt = wk[tt];
      #pragma unroll
      for (int j=0;j<8;j++) acc[j] += wt * bf2f(((bf16*)&vv)[j]);
    }
    short8 o = *(short8*)&ob[(size_t)lr*DH_ + dhg*8];
    #pragma unroll
    for (int j=0;j<8;j++) ((bf16*)&o)[j] = f2bf(bf2f(((bf16*)&o)[j]) + acc[j]);
    *(short8*)&ob[(size_t)lr*DH_ + dhg*8] = o;
  }
}

// ---------------- final GEMM (MFMA, LDS-staged): out = x + gather(outh) @ WT2^T + b_out ----------------
__global__ __launch_bounds__(256) void k_mm_out2(const bf16* __restrict__ Ahd, const bf16* __restrict__ WT2,
    const float* __restrict__ bias, const float* __restrict__ xin, float* __restrict__ out){
  __shared__ __align__(16) bf16 As[128][72];
  __shared__ __align__(16) bf16 Bs[128][72];
  int t = threadIdx.x;
  int w = t>>6, lane = t&63, qd = lane>>4, n = lane&15;
  int wm = w>>1, wn = w&1;
  int r0 = blockIdx.x*128, c0 = blockIdx.y*128;
  f32x4 acc[4][4];
  #pragma unroll
  for (int i=0;i<4;i++)
    #pragma unroll
    for (int j=0;j<4;j++) acc[i][j] = (f32x4){0.f,0.f,0.f,0.f};
  int srow = t>>3, skc = t&7;
  for (int k0=0; k0<512; k0+=64){
    int h = k0 >> 6;
    #pragma unroll
    for (int ch=0; ch<4; ch++){
      int m = ch*32 + srow;
      int r = r0 + m, b = r>>13, nn = r&8191;
      *(short8*)&As[m][skc*8] = *(const short8*)&Ahd[((size_t)(b*H_+h)*N_ + nn)*DH_ + skc*8];
      *(short8*)&Bs[m][skc*8] = *(const short8*)&WT2[(size_t)(c0+m)*512 + k0 + skc*8];
    }
    __syncthreads();
    #pragma unroll
    for (int ksub=0; ksub<2; ksub++){
      short8 af[4], bfr[4];
      #pragma unroll
      for (int i=0;i<4;i++) af[i]  = *(const short8*)&As[wm*64+i*16+n][ksub*32+qd*8];
      #pragma unroll
      for (int j=0;j<4;j++) bfr[j] = *(const short8*)&Bs[wn*64+j*16+n][ksub*32+qd*8];
      #pragma unroll
      for (int i=0;i<4;i++)
        #pragma unroll
        for (int j=0;j<4;j++) acc[i][j] = mfma16(af[i], bfr[j], acc[i][j]);
    }
    __syncthreads();
  }
  #pragma unroll
  for (int i=0;i<4;i++){
    #pragma unroll
    for (int j=0;j<4;j++){
      int c = c0 + wn*64 + j*16 + n;
      #pragma unroll
      for (int rg=0; rg<4; rg++){
        int r = r0 + wm*64 + i*16 + qd*4 + rg;
        out[(size_t)r*512 + c] = acc[i][j][rg] + bias[c] + xin[(size_t)r*512 + c];
      }
    }
  }
}

extern "C" void kernel_launch(void* const* d_in, const int* in_sizes, int n_in,
                              void* d_out, int out_size, void* d_ws, size_t ws_size,
                              hipStream_t stream) {
  const float* x     = (const float*)d_in[0];
  const float* gamma = (const float*)d_in[1];
  const float* beta  = (const float*)d_in[2];
  const float* wqkv  = (const float*)d_in[3];
  const float* resk  = (const float*)d_in[4];
  const float* wout  = (const float*)d_in[5];
  const float* bout  = (const float*)d_in[6];
  float* out = (float*)d_out;

  const size_t SL = (size_t)B_*H_*N_*DH_;
  const size_t SM = (size_t)B_*H_*M_*DH_;
  const size_t SP = (size_t)B_*H_*M_*M_;

  bf16* xn  = (bf16*)d_ws;     // reused as: flash partial OP, then pinv P1..P4, then outh
  bf16* q   = xn + SL;
  bf16* k   = q + SL;
  bf16* v   = k + SL;
  bf16* vT  = v + SL;
  bf16* ql  = vT + SL;
  bf16* kl  = ql + SM;
  bf16* kv3 = kl + SM;
  bf16* z2T = kv3 + SM;
  float* A2 = (float*)(z2T + SM);
  bf16* WT  = (bf16*)(A2 + SP);       // 1536 x 512 bf16
  bf16* WT2 = WT + (size_t)1536*512;  // 512 x 512 bf16
  float* P1 = (float*)xn;             // pinv scratch aliases xn (4*SP*4B == SL*2B)
  float* P2 = P1 + SP;
  float* P3 = P2 + SP;
  float* P4 = P3 + SP;
  float* OPp = (float*)xn;
  float* MPp = (float*)z2T;
  float* LPp = MPp + (size_t)NSPLIT*B_*H_*M_;

  k_wt<<<dim3(24, 8), 256, 0, stream>>>(wqkv, WT, 512, 1536);
  k_wt<<<dim3(8, 8), 256, 0, stream>>>(wout, WT2, 512, 512);
  k_layernorm<<<B_*N_, 256, 0, stream>>>(x, gamma, beta, xn);
  k_mm_qkv2<<<dim3(256, 12), 256, 0, stream>>>(xn, WT, q, k, v);
  k_transp_v<<<dim3(128, 32), 256, 0, stream>>>(v, vT);
  k_landmark<<<B_*H_*M_, 64, 0, stream>>>(q, k, ql, kl);

  // attn3 flash (split + merge) runs BEFORE pinv so partials can use the dead xn/z2T regions
  k_flash_split<<<dim3(NSPLIT, B_*H_), 256, 0, stream>>>(ql, k, vT, OPp, MPp, LPp);
  k_flash_merge<<<dim3(M_/4, B_*H_), 256, 0, stream>>>(OPp, MPp, LPp, kv3);

  k_attn2<<<B_*H_*M_, 256, 0, stream>>>(ql, kl, A2);
  k_pinv_init<<<B_*H_, 256, 0, stream>>>(A2, P1);

  float* Zi = P1; float* Zo = P3;
  for (int it=0; it<6; ++it){
    int sp = (it < 2) ? 0 : 1;   // early NS iterations plain bf16; later split-precision
    k_gemm_pm<<<dim3(16,32), 256, 0, stream>>>(P2, A2, Zi, 0.f,0, 0.f,0, 1.f, sp);    // P = A2@Z
    k_gemm_pm<<<dim3(16,32), 256, 0, stream>>>(Zo, P2, P2, 7.f,1, 15.f,1, 1.f, sp);   // S = 15I - P@(7I-P)
    k_gemm_pm<<<dim3(16,32), 256, 0, stream>>>(P4, P2, Zo, 0.f,0, 13.f,1, 1.f, sp);   // U = 13I - P@S
    k_gemm_pm<<<dim3(16,32), 256, 0, stream>>>(Zo, Zi, P4, 0.f,0, 0.f,0, 0.25f, sp);  // Zn = 0.25*Z@U
    float* tt = Zi; Zi = Zo; Zo = tt;
  }

  k_gemm_z2<<<dim3(4, B_*H_), 256, 0, stream>>>(z2T, Zi, kv3);
  k_flash_w3<<<dim3(N_/256, B_*H_), 256, 0, stream>>>(q, kl, z2T, xn);
  k_conv_add<<<dim3(N_/CCH, B_*H_), 256, 0, stream>>>(v, resk, xn);
  k_mm_out2<<<dim3(256, 4), 256, 0, stream>>>(xn, WT2, bout, x, out);
}

// Round 3
// 911.113 us; speedup vs baseline: 1.1817x; 1.0158x over previous
//
#include <hip/hip_runtime.h>
#include <hip/hip_bf16.h>

#define B_ 4
#define N_ 8192
#define D_ 512
#define H_ 8
#define DH_ 64
#define M_ 256
#define LCH 32
#define KER_ 33
#define NSPLIT 16
#define CS (N_/NSPLIT)   // 512 cols per split chunk

typedef __hip_bfloat16 bf16;
typedef __attribute__((ext_vector_type(8))) short short8;
typedef __attribute__((ext_vector_type(4))) float f32x4;

__device__ __forceinline__ float bf2f(bf16 h){ return __bfloat162float(h); }
__device__ __forceinline__ bf16 f2bf(float f){ return __float2bfloat16(f); }
__device__ __forceinline__ f32x4 mfma16(short8 a, short8 b, f32x4 c){
  return __builtin_amdgcn_mfma_f32_16x16x32_bf16(a, b, c, 0, 0, 0);
}
// async global->LDS, 16B per lane; LDS dest wave-uniform base + lane*16
__device__ __forceinline__ void gload_lds16(const bf16* g, bf16* l){
  __builtin_amdgcn_global_load_lds((const __attribute__((address_space(1))) void*)g,
                                   (__attribute__((address_space(3))) void*)l, 16, 0, 0);
}

// ---------------- LayerNorm: x (b,n,512) fp32 -> xn bf16 ----------------
__global__ __launch_bounds__(256) void k_layernorm(const float* __restrict__ x,
    const float* __restrict__ gamma, const float* __restrict__ beta,
    bf16* __restrict__ xn){
  int row = blockIdx.x;
  const float* xr = x + (size_t)row * D_;
  bf16* o = xn + (size_t)row * D_;
  int t = threadIdx.x;
  float v0 = xr[t], v1 = xr[t+256];
  float s = v0+v1, ss = v0*v0 + v1*v1;
  __shared__ float sh[8];
  for (int off=32; off; off>>=1){ s += __shfl_xor(s,off); ss += __shfl_xor(ss,off); }
  int lane = t&63, wid = t>>6;
  if (lane==0){ sh[wid] = s; sh[wid+4] = ss; }
  __syncthreads();
  float S  = sh[0]+sh[1]+sh[2]+sh[3];
  float SS = sh[4]+sh[5]+sh[6]+sh[7];
  float mu = S*(1.f/D_);
  float var = SS*(1.f/D_) - mu*mu;
  float rs = rsqrtf(var + 1e-5f);
  o[t]     = f2bf((v0-mu)*rs*gamma[t]     + beta[t]);
  o[t+256] = f2bf((v1-mu)*rs*gamma[t+256] + beta[t+256]);
}

// ---------------- W transpose+convert: W (RxC fp32) -> WT (CxR bf16) ----------------
__global__ __launch_bounds__(256) void k_wt(const float* __restrict__ W, bf16* __restrict__ WT,
    int R, int C){
  int c0 = blockIdx.x*64, r0 = blockIdx.y*64;
  __shared__ float tile[64][65];
  int t = threadIdx.x;
  for (int i=t;i<4096;i+=256){ int r=i>>6, c=i&63; tile[r][c] = W[(size_t)(r0+r)*C + c0+c]; }
  __syncthreads();
  for (int i=t;i<512;i+=256){
    int c=i>>3, rg=i&7;
    short8 o;
    #pragma unroll
    for (int j=0;j<8;j++) ((bf16*)&o)[j] = f2bf(tile[rg*8+j][c]);
    *(short8*)&WT[(size_t)(c0+c)*R + r0 + rg*8] = o;
  }
}

// ---------------- QKV GEMM (MFMA, global_load_lds staged, linear LDS): xn @ WT^T -> q,k,v ----------------
__global__ __launch_bounds__(256) void k_mm_qkv3(const bf16* __restrict__ A, const bf16* __restrict__ WT,
    bf16* __restrict__ qbuf, bf16* __restrict__ kbuf, bf16* __restrict__ vbuf){
  __shared__ __align__(16) bf16 As[128][64];
  __shared__ __align__(16) bf16 Bs[128][64];
  int t = threadIdx.x;
  int w = t>>6, lane = t&63, qd = lane>>4, n = lane&15;
  int wm = w>>1, wn = w&1;
  int r0 = blockIdx.x*128, c0 = blockIdx.y*128;
  int lrow = w*8 + (lane>>3);      // staging row within each 32-row group
  int lcol = (lane&7)*8;           // staging col (elements), 16B chunk per lane
  f32x4 acc[4][4];
  #pragma unroll
  for (int i=0;i<4;i++)
    #pragma unroll
    for (int j=0;j<4;j++) acc[i][j] = (f32x4){0.f,0.f,0.f,0.f};
  for (int k0=0; k0<512; k0+=64){
    #pragma unroll
    for (int ch=0; ch<4; ch++){
      int m = ch*32 + lrow;
      gload_lds16(&A [(size_t)(r0+m)*512 + k0 + lcol], &As[ch*32 + w*8][0]);
      gload_lds16(&WT[(size_t)(c0+m)*512 + k0 + lcol], &Bs[ch*32 + w*8][0]);
    }
    __syncthreads();
    #pragma unroll
    for (int ksub=0; ksub<2; ksub++){
      short8 af[4], bfr[4];
      #pragma unroll
      for (int i=0;i<4;i++) af[i]  = *(const short8*)&As[wm*64+i*16+n][ksub*32+qd*8];
      #pragma unroll
      for (int j=0;j<4;j++) bfr[j] = *(const short8*)&Bs[wn*64+j*16+n][ksub*32+qd*8];
      #pragma unroll
      for (int i=0;i<4;i++)
        #pragma unroll
        for (int j=0;j<4;j++) acc[i][j] = mfma16(af[i], bfr[j], acc[i][j]);
    }
    __syncthreads();
  }
  int part = c0 >> 9;
  bf16* dst = (part==0)? qbuf : (part==1)? kbuf : vbuf;
  float scale = (part==0)? 0.125f : 1.f;
  #pragma unroll
  for (int i=0;i<4;i++){
    #pragma unroll
    for (int j=0;j<4;j++){
      int c = c0 + wn*64 + j*16 + n;
      int cc = c & 511, h = cc>>6, dh = cc&63;
      #pragma unroll
      for (int rg=0; rg<4; rg++){
        int r = r0 + wm*64 + i*16 + qd*4 + rg;
        int b = r >> 13, nn = r & 8191;
        dst[(((size_t)(b*H_+h))*N_ + nn)*DH_ + dh] = f2bf(acc[i][j][rg]*scale);
      }
    }
  }
}

// ---------------- v -> vT tiled transpose (64x64) ----------------
__global__ __launch_bounds__(256) void k_transp_v(const bf16* __restrict__ v, bf16* __restrict__ vT){
  int bh = blockIdx.y, n0 = blockIdx.x*64;
  __shared__ bf16 tile[64][72];
  const bf16* vb = v + (size_t)bh*N_*DH_;
  int t = threadIdx.x;
  for (int i=t; i<512; i+=256){
    int r = i>>3, cg = i&7;
    *(short8*)&tile[r][cg*8] = *(const short8*)&vb[(size_t)(n0+r)*DH_ + cg*8];
  }
  __syncthreads();
  bf16* ob = vT + (size_t)bh*DH_*N_;
  for (int i=t; i<512; i+=256){
    int dh = i>>3, ng = i&7;
    short8 o;
    #pragma unroll
    for (int j=0;j<8;j++) ((bf16*)&o)[j] = tile[ng*8+j][dh];
    *(short8*)&ob[(size_t)dh*N_ + n0 + ng*8] = o;
  }
}

// ---------------- landmark means over contiguous 32-row chunks ----------------
__global__ __launch_bounds__(64) void k_landmark(const bf16* __restrict__ q, const bf16* __restrict__ k,
    bf16* __restrict__ ql, bf16* __restrict__ kl){
  int bhm = blockIdx.x;
  int bh = bhm >> 8, m = bhm & 255;
  int dh = threadIdx.x;
  const bf16* qp = q + ((size_t)bh*N_ + (size_t)m*LCH)*DH_ + dh;
  const bf16* kp = k + ((size_t)bh*N_ + (size_t)m*LCH)*DH_ + dh;
  float sq=0.f, sk=0.f;
  #pragma unroll
  for (int j=0;j<LCH;j++){ sq += bf2f(qp[(size_t)j*DH_]); sk += bf2f(kp[(size_t)j*DH_]); }
  ql[((size_t)bh*M_ + m)*DH_ + dh] = f2bf(sq*(1.f/LCH));
  kl[((size_t)bh*M_ + m)*DH_ + dh] = f2bf(sk*(1.f/LCH));
}

// ---------------- attn2 = softmax(q_l @ k_l^T) rows (fp32 out) ----------------
__global__ __launch_bounds__(256) void k_attn2(const bf16* __restrict__ ql, const bf16* __restrict__ kl,
    float* __restrict__ A2){
  int bhm = blockIdx.x;
  int bh = bhm >> 8, m = bhm & 255;
  int t = threadIdx.x;
  __shared__ float qrow[64];
  __shared__ float sh[4];
  if (t < 64) qrow[t] = bf2f(ql[((size_t)bh*M_ + m)*DH_ + t]);
  __syncthreads();
  const bf16* krow = kl + ((size_t)bh*M_ + t)*DH_;
  float s = 0.f;
  #pragma unroll
  for (int i=0;i<64;i++) s += qrow[i]*bf2f(krow[i]);
  float mx = s;
  for (int off=32; off; off>>=1) mx = fmaxf(mx, __shfl_xor(mx, off));
  if ((t&63)==0) sh[t>>6] = mx;
  __syncthreads();
  mx = fmaxf(fmaxf(sh[0],sh[1]), fmaxf(sh[2],sh[3]));
  float e = expf(s - mx);
  float sum = e;
  for (int off=32; off; off>>=1) sum += __shfl_xor(sum, off);
  __syncthreads();
  if ((t&63)==0) sh[t>>6] = sum;
  __syncthreads();
  sum = sh[0]+sh[1]+sh[2]+sh[3];
  A2[((size_t)bh*M_ + m)*M_ + t] = e/sum;
}

// ---------------- pinv init: Z = A^T / (max_rowsum * max_colsum) ----------------
__global__ __launch_bounds__(256) void k_pinv_init(const float* __restrict__ A2, float* __restrict__ Z){
  int bh = blockIdx.x;
  int t = threadIdx.x;
  const float* Ab = A2 + (size_t)bh*M_*M_;
  float* Zb = Z + (size_t)bh*M_*M_;
  float cs=0.f, rsm=0.f;
  for (int r=0;r<M_;r++) cs += fabsf(Ab[(size_t)r*M_ + t]);
  for (int c=0;c<M_;c++) rsm += fabsf(Ab[(size_t)t*M_ + c]);
  __shared__ float sh[4];
  float v = cs;
  for (int off=32; off; off>>=1) v = fmaxf(v, __shfl_xor(v, off));
  if ((t&63)==0) sh[t>>6] = v;
  __syncthreads();
  float maxc = fmaxf(fmaxf(sh[0],sh[1]), fmaxf(sh[2],sh[3]));
  __syncthreads();
  v = rsm;
  for (int off=32; off; off>>=1) v = fmaxf(v, __shfl_xor(v, off));
  if ((t&63)==0) sh[t>>6] = v;
  __syncthreads();
  float maxr = fmaxf(fmaxf(sh[0],sh[1]), fmaxf(sh[2],sh[3]));
  float inv = 1.f/(maxr*maxc);
  for (int r=0;r<M_;r++) Zb[(size_t)r*M_ + t] = Ab[(size_t)t*M_ + r]*inv;
}

// ---------------- pinv GEMM (bf16 MFMA; optional hi/lo split precision) ----------------
__global__ __launch_bounds__(256) void k_gemm_pm(float* __restrict__ C, const float* __restrict__ A,
    const float* __restrict__ Bm, float bDiag, int bNeg, float cDiag, int cNeg, float cScale,
    int split){
  int bh = blockIdx.y;
  int tm = blockIdx.x >> 2, tn = blockIdx.x & 3;
  const float* Ab = A  + (size_t)bh*65536;
  const float* Bb = Bm + (size_t)bh*65536;
  float* Cb = C + (size_t)bh*65536;
  __shared__ __align__(16) bf16 Ah[64][72];
  __shared__ __align__(16) bf16 Al[64][72];
  __shared__ __align__(16) bf16 Bh[64][72];
  __shared__ __align__(16) bf16 Bl[64][72];
  int t = threadIdx.x;
  int w = t>>6, lane = t&63, qd = lane>>4, n = lane&15;
  int wm = w>>1, wn = w&1;
  int r0 = tm*64, c0 = tn*64;
  f32x4 acc[2][2];
  #pragma unroll
  for (int i=0;i<2;i++)
    #pragma unroll
    for (int j=0;j<2;j++) acc[i][j] = (f32x4){0.f,0.f,0.f,0.f};
  int srow = t>>3, skc = t&7;
  for (int k0=0; k0<256; k0+=64){
    #pragma unroll
    for (int ch=0; ch<2; ch++){
      int m = ch*32 + srow;
      short8 vh, vl;
      const float* ap = &Ab[(size_t)(r0+m)*256 + k0 + skc*8];
      #pragma unroll
      for (int j=0;j<8;j++){
        float x = ap[j];
        bf16 h = f2bf(x);
        ((bf16*)&vh)[j] = h;
        if (split) ((bf16*)&vl)[j] = f2bf(x - bf2f(h));
      }
      *(short8*)&Ah[m][skc*8] = vh;
      if (split) *(short8*)&Al[m][skc*8] = vl;
      const float* bp = &Bb[(size_t)(k0+m)*256 + c0 + skc*8];
      int kr = k0 + m;
      #pragma unroll
      for (int j=0;j<8;j++){
        float x = bp[j];
        if (bNeg) x = (kr == (c0 + skc*8 + j) ? bDiag : 0.f) - x;
        bf16 h = f2bf(x);
        ((bf16*)&vh)[j] = h;
        if (split) ((bf16*)&vl)[j] = f2bf(x - bf2f(h));
      }
      #pragma unroll
      for (int j=0;j<8;j++){
        Bh[skc*8+j][m] = ((bf16*)&vh)[j];
        if (split) Bl[skc*8+j][m] = ((bf16*)&vl)[j];
      }
    }
    __syncthreads();
    #pragma unroll
    for (int ksub=0; ksub<2; ksub++){
      short8 afh[2], afl[2], bfh[2], bfl[2];
      #pragma unroll
      for (int i=0;i<2;i++){
        afh[i] = *(const short8*)&Ah[wm*32+i*16+n][ksub*32+qd*8];
        if (split) afl[i] = *(const short8*)&Al[wm*32+i*16+n][ksub*32+qd*8];
      }
      #pragma unroll
      for (int j=0;j<2;j++){
        bfh[j] = *(const short8*)&Bh[wn*32+j*16+n][ksub*32+qd*8];
        if (split) bfl[j] = *(const short8*)&Bl[wn*32+j*16+n][ksub*32+qd*8];
      }
      #pragma unroll
      for (int i=0;i<2;i++)
        #pragma unroll
        for (int j=0;j<2;j++){
          if (split){
            acc[i][j] = mfma16(afl[i], bfh[j], acc[i][j]);
            acc[i][j] = mfma16(afh[i], bfl[j], acc[i][j]);
          }
          acc[i][j] = mfma16(afh[i], bfh[j], acc[i][j]);
        }
    }
    __syncthreads();
  }
  #pragma unroll
  for (int i=0;i<2;i++){
    #pragma unroll
    for (int j=0;j<2;j++){
      int cidx = c0 + wn*32 + j*16 + n;
      #pragma unroll
      for (int rg=0; rg<4; rg++){
        int r = r0 + wm*32 + i*16 + qd*4 + rg;
        float r_ = acc[i][j][rg];
        if (cNeg) r_ = ((r==cidx)? cDiag : 0.f) - r_;
        Cb[(size_t)r*256 + cidx] = r_*cScale;
      }
    }
  }
}

// ---------------- batched GEMM 256x64x256: z2T = (Z @ kv3)^T ----------------
__global__ __launch_bounds__(256) void k_gemm_z2(bf16* __restrict__ z2t, const float* __restrict__ A,
    const bf16* __restrict__ Bm){
  int bh = blockIdx.y;
  int tm = blockIdx.x;
  const float* Ab = A  + (size_t)bh*65536;
  const bf16* Bb = Bm + (size_t)bh*M_*DH_;
  __shared__ float As[16][68];
  __shared__ float Bs[16][64];
  int t = threadIdx.x, tx = t&15, ty = t>>4;
  int r0 = tm*64;
  float acc[4][4] = {};
  for (int k0=0;k0<256;k0+=16){
    for (int i=t;i<1024;i+=256){
      int m=i>>4, kq=i&15;
      As[kq][m] = Ab[(size_t)(r0+m)*256 + k0+kq];
      int nn=i&63, k2=i>>6;
      Bs[k2][nn] = bf2f(Bb[(size_t)(k0+k2)*64 + nn]);
    }
    __syncthreads();
    #pragma unroll
    for (int kq=0;kq<16;kq++){
      float a0[4], b0[4];
      #pragma unroll
      for (int i=0;i<4;i++) a0[i] = As[kq][ty*4+i];
      #pragma unroll
      for (int j=0;j<4;j++) b0[j] = Bs[kq][tx*4+j];
      #pragma unroll
      for (int i=0;i<4;i++)
        #pragma unroll
        for (int j=0;j<4;j++) acc[i][j] += a0[i]*b0[j];
    }
    __syncthreads();
  }
  #pragma unroll
  for (int i=0;i<4;i++){
    int r = r0+ty*4+i;
    #pragma unroll
    for (int j=0;j<4;j++)
      z2t[(size_t)bh*16384 + (size_t)(tx*4+j)*256 + r] = f2bf(acc[i][j]);
  }
}

// ---------------- attn3 flash, flash-decoding split over columns ----------------
__global__ __launch_bounds__(256, 2) void k_flash_split(const bf16* __restrict__ Q,
    const bf16* __restrict__ K, const bf16* __restrict__ VT,
    float* __restrict__ OP, float* __restrict__ MP, float* __restrict__ LP){
  int bh = blockIdx.y;
  int sp = blockIdx.x;
  int t = threadIdx.x, w = t>>6, lane = t&63, qd = lane>>4, n = lane&15;
  int r0 = w*64;
  const size_t Qoff = ((size_t)bh*M_ + r0)*DH_;
  const size_t Koff = ((size_t)bh*N_ + (size_t)sp*CS)*DH_;
  const size_t Voff = (size_t)bh*DH_*N_ + (size_t)sp*CS;
  __shared__ __align__(16) bf16 pbuf[4][4][16][72];
  short8 aq[4][2];
  #pragma unroll
  for (int rt=0; rt<4; rt++){
    aq[rt][0] = *(const short8*)&Q[Qoff + (size_t)(rt*16+n)*DH_ + qd*8];
    aq[rt][1] = *(const short8*)&Q[Qoff + (size_t)(rt*16+n)*DH_ + 32 + qd*8];
  }
  f32x4 o[4][4];
  float mrun[4][4], lrun[4][4];
  #pragma unroll
  for (int rt=0; rt<4; rt++){
    #pragma unroll
    for (int j=0;j<4;j++){ o[rt][j] = (f32x4){0.f,0.f,0.f,0.f}; mrun[rt][j] = -1e30f; lrun[rt][j] = 0.f; }
  }
  for (int tl=0; tl<CS/64; ++tl){
    const bf16* kp = K + Koff + (size_t)(tl*64)*DH_;
    short8 kb[4][2];
    #pragma unroll
    for (int cg=0; cg<4; cg++){
      kb[cg][0] = *(const short8*)&kp[(size_t)(cg*16+n)*DH_ + qd*8];
      kb[cg][1] = *(const short8*)&kp[(size_t)(cg*16+n)*DH_ + 32 + qd*8];
    }
    #pragma unroll
    for (int rt=0; rt<4; rt++){
      f32x4 s[4];
      #pragma unroll
      for (int cg=0; cg<4; cg++){
        f32x4 z = (f32x4){0.f,0.f,0.f,0.f};
        z = mfma16(aq[rt][0], kb[cg][0], z);
        z = mfma16(aq[rt][1], kb[cg][1], z);
        s[cg] = z;
      }
      float alpha[4];
      #pragma unroll
      for (int rg=0; rg<4; rg++){
        float smax = fmaxf(fmaxf(s[0][rg],s[1][rg]), fmaxf(s[2][rg],s[3][rg]));
        smax = fmaxf(smax, __shfl_xor(smax, 1));
        smax = fmaxf(smax, __shfl_xor(smax, 2));
        smax = fmaxf(smax, __shfl_xor(smax, 4));
        smax = fmaxf(smax, __shfl_xor(smax, 8));
        float mn = fmaxf(mrun[rt][rg], smax);
        float p0 = __expf(s[0][rg]-mn), p1 = __expf(s[1][rg]-mn);
        float p2 = __expf(s[2][rg]-mn), p3 = __expf(s[3][rg]-mn);
        float ts = p0+p1+p2+p3;
        ts += __shfl_xor(ts,1); ts += __shfl_xor(ts,2);
        ts += __shfl_xor(ts,4); ts += __shfl_xor(ts,8);
        float al = __expf(mrun[rt][rg]-mn);
        lrun[rt][rg] = lrun[rt][rg]*al + ts;
        mrun[rt][rg] = mn;
        alpha[rg] = al;
        pbuf[w][rt][qd*4+rg][n]    = f2bf(p0);
        pbuf[w][rt][qd*4+rg][16+n] = f2bf(p1);
        pbuf[w][rt][qd*4+rg][32+n] = f2bf(p2);
        pbuf[w][rt][qd*4+rg][48+n] = f2bf(p3);
      }
      #pragma unroll
      for (int dg=0; dg<4; dg++)
        #pragma unroll
        for (int rg=0; rg<4; rg++) o[rt][dg][rg] *= alpha[rg];
    }
    const bf16* vp = VT + Voff + tl*64 + qd*8;
    short8 vb[4][2];
    #pragma unroll
    for (int dg=0; dg<4; dg++){
      vb[dg][0] = *(const short8*)&vp[(size_t)(dg*16+n)*N_];
      vb[dg][1] = *(const short8*)&vp[(size_t)(dg*16+n)*N_ + 32];
    }
    #pragma unroll
    for (int rt=0; rt<4; rt++){
      short8 ap0 = *(const short8*)&pbuf[w][rt][n][qd*8];
      short8 ap1 = *(const short8*)&pbuf[w][rt][n][32+qd*8];
      #pragma unroll
      for (int dg=0; dg<4; dg++){
        o[rt][dg] = mfma16(ap0, vb[dg][0], o[rt][dg]);
        o[rt][dg] = mfma16(ap1, vb[dg][1], o[rt][dg]);
      }
    }
  }
  size_t base = ((size_t)sp*(B_*H_) + bh)*M_;
  #pragma unroll
  for (int rt=0; rt<4; rt++){
    #pragma unroll
    for (int rg=0; rg<4; rg++){
      int row = r0 + rt*16 + qd*4 + rg;
      if (n==0){ MP[base+row] = mrun[rt][rg]; LP[base+row] = lrun[rt][rg]; }
      #pragma unroll
      for (int dg=0; dg<4; dg++)
        OP[(base+row)*DH_ + dg*16 + n] = o[rt][dg][rg];
    }
  }
}

// ---------------- merge NSPLIT flash partials -> kv3 ----------------
__global__ __launch_bounds__(256) void k_flash_merge(const float* __restrict__ OP,
    const float* __restrict__ MP, const float* __restrict__ LP, bf16* __restrict__ O){
  int bh = blockIdx.y;
  int r = blockIdx.x*4 + (threadIdx.x>>6);
  int dh = threadIdx.x & 63;
  float M = -1e30f, acc = 0.f, den = 0.f;
  for (int s=0; s<NSPLIT; s++){
    size_t base = ((size_t)s*(B_*H_) + bh)*M_ + r;
    float m = MP[base];
    float l = LP[base];
    float ov = OP[base*DH_ + dh];
    float Mn = fmaxf(M, m);
    float wo = __expf(M - Mn), wn = __expf(m - Mn);
    acc = acc*wo + ov*wn;
    den = den*wo + l*wn;
    M = Mn;
  }
  O[((size_t)bh*M_ + r)*DH_ + dh] = f2bf(acc/den);
}

// ---------------- attn1 flash, split-structured: 4 waves x 4 rowtiles, 64-col tiles ----------------
__global__ __launch_bounds__(256, 2) void k_flash_w3(const bf16* __restrict__ Q,
    const bf16* __restrict__ K, const bf16* __restrict__ VT, bf16* __restrict__ O){
  int bh = blockIdx.y;
  int t = threadIdx.x, w = t>>6, lane = t&63, qd = lane>>4, n = lane&15;
  int r0 = blockIdx.x*256 + w*64;
  const size_t Qoff = ((size_t)bh*N_ + r0)*DH_;
  const size_t Koff = (size_t)bh*M_*DH_;
  const size_t Voff = (size_t)bh*DH_*M_;
  __shared__ __align__(16) bf16 pbuf[4][4][16][72];
  short8 aq[4][2];
  #pragma unroll
  for (int rt=0; rt<4; rt++){
    aq[rt][0] = *(const short8*)&Q[Qoff + (size_t)(rt*16+n)*DH_ + qd*8];
    aq[rt][1] = *(const short8*)&Q[Qoff + (size_t)(rt*16+n)*DH_ + 32 + qd*8];
  }
  f32x4 o[4][4];
  float mrun[4][4], lrun[4][4];
  #pragma unroll
  for (int rt=0; rt<4; rt++){
    #pragma unroll
    for (int j=0;j<4;j++){ o[rt][j] = (f32x4){0.f,0.f,0.f,0.f}; mrun[rt][j] = -1e30f; lrun[rt][j] = 0.f; }
  }
  #pragma unroll
  for (int tl=0; tl<4; ++tl){
    const bf16* kp = K + Koff + (size_t)(tl*64)*DH_;
    short8 kb[4][2];
    #pragma unroll
    for (int cg=0; cg<4; cg++){
      kb[cg][0] = *(const short8*)&kp[(size_t)(cg*16+n)*DH_ + qd*8];
      kb[cg][1] = *(const short8*)&kp[(size_t)(cg*16+n)*DH_ + 32 + qd*8];
    }
    #pragma unroll
    for (int rt=0; rt<4; rt++){
      f32x4 s[4];
      #pragma unroll
      for (int cg=0; cg<4; cg++){
        f32x4 z = (f32x4){0.f,0.f,0.f,0.f};
        z = mfma16(aq[rt][0], kb[cg][0], z);
        z = mfma16(aq[rt][1], kb[cg][1], z);
        s[cg] = z;
      }
      float alpha[4];
      #pragma unroll
      for (int rg=0; rg<4; rg++){
        float smax = fmaxf(fmaxf(s[0][rg],s[1][rg]), fmaxf(s[2][rg],s[3][rg]));
        smax = fmaxf(smax, __shfl_xor(smax, 1));
        smax = fmaxf(smax, __shfl_xor(smax, 2));
        smax = fmaxf(smax, __shfl_xor(smax, 4));
        smax = fmaxf(smax, __shfl_xor(smax, 8));
        float mn = fmaxf(mrun[rt][rg], smax);
        float p0 = __expf(s[0][rg]-mn), p1 = __expf(s[1][rg]-mn);
        float p2 = __expf(s[2][rg]-mn), p3 = __expf(s[3][rg]-mn);
        float ts = p0+p1+p2+p3;
        ts += __shfl_xor(ts,1); ts += __shfl_xor(ts,2);
        ts += __shfl_xor(ts,4); ts += __shfl_xor(ts,8);
        float al = __expf(mrun[rt][rg]-mn);
        lrun[rt][rg] = lrun[rt][rg]*al + ts;
        mrun[rt][rg] = mn;
        alpha[rg] = al;
        pbuf[w][rt][qd*4+rg][n]    = f2bf(p0);
        pbuf[w][rt][qd*4+rg][16+n] = f2bf(p1);
        pbuf[w][rt][qd*4+rg][32+n] = f2bf(p2);
        pbuf[w][rt][qd*4+rg][48+n] = f2bf(p3);
      }
      #pragma unroll
      for (int dg=0; dg<4; dg++)
        #pragma unroll
        for (int rg=0; rg<4; rg++) o[rt][dg][rg] *= alpha[rg];
    }
    const bf16* vp = VT + Voff + tl*64 + qd*8;
    short8 vb[4][2];
    #pragma unroll
    for (int dg=0; dg<4; dg++){
      vb[dg][0] = *(const short8*)&vp[(size_t)(dg*16+n)*M_];
      vb[dg][1] = *(const short8*)&vp[(size_t)(dg*16+n)*M_ + 32];
    }
    #pragma unroll
    for (int rt=0; rt<4; rt++){
      short8 ap0 = *(const short8*)&pbuf[w][rt][n][qd*8];
      short8 ap1 = *(const short8*)&pbuf[w][rt][n][32+qd*8];
      #pragma unroll
      for (int dg=0; dg<4; dg++){
        o[rt][dg] = mfma16(ap0, vb[dg][0], o[rt][dg]);
        o[rt][dg] = mfma16(ap1, vb[dg][1], o[rt][dg]);
      }
    }
  }
  #pragma unroll
  for (int rt=0; rt<4; rt++){
    #pragma unroll
    for (int rg=0; rg<4; rg++){
      float inv = 1.f/lrun[rt][rg];
      size_t rowoff = ((size_t)bh*N_ + r0 + rt*16 + qd*4 + rg)*DH_;
      #pragma unroll
      for (int dg=0; dg<4; dg++)
        O[rowoff + dg*16 + n] = f2bf(o[rt][dg][rg]*inv);
    }
  }
}

// ---------------- depthwise conv(KER=33), LDS-tiled, vectorized RMW into outh ----------------
#define CCH 256
__global__ __launch_bounds__(256) void k_conv_add(const bf16* __restrict__ v, const float* __restrict__ w,
    bf16* __restrict__ outh){
  int bh = blockIdx.y;
  int n0 = blockIdx.x * CCH;
  int h = bh & 7;
  __shared__ bf16 vs[CCH+32][72];
  __shared__ float wk[KER_];
  int t = threadIdx.x;
  if (t < KER_) wk[t] = w[h*KER_ + t];
  const bf16* vb = v + (size_t)bh*N_*DH_;
  for (int i=t; i<(CCH+32)*8; i+=256){
    int r = i>>3, cg = i&7;
    int nn = n0 - 16 + r;
    short8 val = {0,0,0,0,0,0,0,0};
    if (nn >= 0 && nn < N_) val = *(const short8*)&vb[(size_t)nn*DH_ + cg*8];
    *(short8*)&vs[r][cg*8] = val;
  }
  __syncthreads();
  int dhg = t & 7, rowg = t >> 3;
  bf16* ob = outh + ((size_t)bh*N_ + n0)*DH_;
  #pragma unroll
  for (int rr=0; rr<8; rr++){
    int lr = rowg*8 + rr;
    float acc[8] = {0.f,0.f,0.f,0.f,0.f,0.f,0.f,0.f};
    for (int tt=0; tt<KER_; tt++){
      short8 vv = *(const short8*)&vs[lr+tt][dhg*8];
      float wt = wk[tt];
      #pragma unroll
      for (int j=0;j<8;j++) acc[j] += wt * bf2f(((bf16*)&vv)[j]);
    }
    short8 o = *(short8*)&ob[(size_t)lr*DH_ + dhg*8];
    #pragma unroll
    for (int j=0;j<8;j++) ((bf16*)&o)[j] = f2bf(bf2f(((bf16*)&o)[j]) + acc[j]);
    *(short8*)&ob[(size_t)lr*DH_ + dhg*8] = o;
  }
}

// ---------------- final GEMM (MFMA, global_load_lds staged): out = x + gather(outh) @ WT2^T + b_out ----------------
__global__ __launch_bounds__(256) void k_mm_out3(const bf16* __restrict__ Ahd, const bf16* __restrict__ WT2,
    const float* __restrict__ bias, const float* __restrict__ xin, float* __restrict__ out){
  __shared__ __align__(16) bf16 As[128][64];
  __shared__ __align__(16) bf16 Bs[128][64];
  int t = threadIdx.x;
  int w = t>>6, lane = t&63, qd = lane>>4, n = lane&15;
  int wm = w>>1, wn = w&1;
  int r0 = blockIdx.x*128, c0 = blockIdx.y*128;
  int lrow = w*8 + (lane>>3);
  int lcol = (lane&7)*8;
  f32x4 acc[4][4];
  #pragma unroll
  for (int i=0;i<4;i++)
    #pragma unroll
    for (int j=0;j<4;j++) acc[i][j] = (f32x4){0.f,0.f,0.f,0.f};
  for (int k0=0; k0<512; k0+=64){
    int h = k0 >> 6;
    #pragma unroll
    for (int ch=0; ch<4; ch++){
      int m = ch*32 + lrow;
      int r = r0 + m, b = r>>13, nn = r&8191;
      gload_lds16(&Ahd[((size_t)(b*H_+h)*N_ + nn)*DH_ + lcol], &As[ch*32 + w*8][0]);
      gload_lds16(&WT2[(size_t)(c0+m)*512 + k0 + lcol], &Bs[ch*32 + w*8][0]);
    }
    __syncthreads();
    #pragma unroll
    for (int ksub=0; ksub<2; ksub++){
      short8 af[4], bfr[4];
      #pragma unroll
      for (int i=0;i<4;i++) af[i]  = *(const short8*)&As[wm*64+i*16+n][ksub*32+qd*8];
      #pragma unroll
      for (int j=0;j<4;j++) bfr[j] = *(const short8*)&Bs[wn*64+j*16+n][ksub*32+qd*8];
      #pragma unroll
      for (int i=0;i<4;i++)
        #pragma unroll
        for (int j=0;j<4;j++) acc[i][j] = mfma16(af[i], bfr[j], acc[i][j]);
    }
    __syncthreads();
  }
  #pragma unroll
  for (int i=0;i<4;i++){
    #pragma unroll
    for (int j=0;j<4;j++){
      int c = c0 + wn*64 + j*16 + n;
      #pragma unroll
      for (int rg=0; rg<4; rg++){
        int r = r0 + wm*64 + i*16 + qd*4 + rg;
        out[(size_t)r*512 + c] = acc[i][j][rg] + bias[c] + xin[(size_t)r*512 + c];
      }
    }
  }
}

extern "C" void kernel_launch(void* const* d_in, const int* in_sizes, int n_in,
                              void* d_out, int out_size, void* d_ws, size_t ws_size,
                              hipStream_t stream) {
  const float* x     = (const float*)d_in[0];
  const float* gamma = (const float*)d_in[1];
  const float* beta  = (const float*)d_in[2];
  const float* wqkv  = (const float*)d_in[3];
  const float* resk  = (const float*)d_in[4];
  const float* wout  = (const float*)d_in[5];
  const float* bout  = (const float*)d_in[6];
  float* out = (float*)d_out;

  const size_t SL = (size_t)B_*H_*N_*DH_;
  const size_t SM = (size_t)B_*H_*M_*DH_;
  const size_t SP = (size_t)B_*H_*M_*M_;

  bf16* xn  = (bf16*)d_ws;     // reused as: flash partial OP, then pinv P1..P4, then outh
  bf16* q   = xn + SL;
  bf16* k   = q + SL;
  bf16* v   = k + SL;
  bf16* vT  = v + SL;
  bf16* ql  = vT + SL;
  bf16* kl  = ql + SM;
  bf16* kv3 = kl + SM;
  bf16* z2T = kv3 + SM;
  float* A2 = (float*)(z2T + SM);
  bf16* WT  = (bf16*)(A2 + SP);       // 1536 x 512 bf16
  bf16* WT2 = WT + (size_t)1536*512;  // 512 x 512 bf16
  float* P1 = (float*)xn;             // pinv scratch aliases xn (4*SP*4B == SL*2B)
  float* P2 = P1 + SP;
  float* P3 = P2 + SP;
  float* P4 = P3 + SP;
  float* OPp = (float*)xn;
  float* MPp = (float*)z2T;
  float* LPp = MPp + (size_t)NSPLIT*B_*H_*M_;

  k_wt<<<dim3(24, 8), 256, 0, stream>>>(wqkv, WT, 512, 1536);
  k_wt<<<dim3(8, 8), 256, 0, stream>>>(wout, WT2, 512, 512);
  k_layernorm<<<B_*N_, 256, 0, stream>>>(x, gamma, beta, xn);
  k_mm_qkv3<<<dim3(256, 12), 256, 0, stream>>>(xn, WT, q, k, v);
  k_transp_v<<<dim3(128, 32), 256, 0, stream>>>(v, vT);
  k_landmark<<<B_*H_*M_, 64, 0, stream>>>(q, k, ql, kl);

  // attn3 flash (split + merge) runs BEFORE pinv so partials can use the dead xn/z2T regions
  k_flash_split<<<dim3(NSPLIT, B_*H_), 256, 0, stream>>>(ql, k, vT, OPp, MPp, LPp);
  k_flash_merge<<<dim3(M_/4, B_*H_), 256, 0, stream>>>(OPp, MPp, LPp, kv3);

  k_attn2<<<B_*H_*M_, 256, 0, stream>>>(ql, kl, A2);
  k_pinv_init<<<B_*H_, 256, 0, stream>>>(A2, P1);

  float* Zi = P1; float* Zo = P3;
  for (int it=0; it<6; ++it){
    int sp = (it < 4) ? 0 : 1;   // first 4 NS iterations plain bf16; last 2 split-precision
    k_gemm_pm<<<dim3(16,32), 256, 0, stream>>>(P2, A2, Zi, 0.f,0, 0.f,0, 1.f, sp);    // P = A2@Z
    k_gemm_pm<<<dim3(16,32), 256, 0, stream>>>(Zo, P2, P2, 7.f,1, 15.f,1, 1.f, sp);   // S = 15I - P@(7I-P)
    k_gemm_pm<<<dim3(16,32), 256, 0, stream>>>(P4, P2, Zo, 0.f,0, 13.f,1, 1.f, sp);   // U = 13I - P@S
    k_gemm_pm<<<dim3(16,32), 256, 0, stream>>>(Zo, Zi, P4, 0.f,0, 0.f,0, 0.25f, sp);  // Zn = 0.25*Z@U
    float* tt = Zi; Zi = Zo; Zo = tt;
  }

  k_gemm_z2<<<dim3(4, B_*H_), 256, 0, stream>>>(z2T, Zi, kv3);
  k_flash_w3<<<dim3(N_/256, B_*H_), 256, 0, stream>>>(q, kl, z2T, xn);
  k_conv_add<<<dim3(N_/CCH, B_*H_), 256, 0, stream>>>(v, resk, xn);
  k_mm_out3<<<dim3(256, 4), 256, 0, stream>>>(xn, WT2, bout, x, out);
}